// Round 1
// 512.315 us; speedup vs baseline: 1.0369x; 1.0369x over previous
//
#include <hip/hip_runtime.h>
#include <hip/hip_bf16.h>
#include <cstdint>
#include <cstddef>

// Problem dims (fixed by reference)
#define B_DIM 4
#define T_DIM 4096
#define D_DIM 2048
#define M_DIM 512
#define NTOK  (B_DIM * T_DIM)     // 16384 rows
#define KCOMB (D_DIM + M_DIM)     // 2560
#define NCHUNK 64                 // chunks per chain for the parallel scan
#define CLEN   64                 // T / NCHUNK

typedef __attribute__((ext_vector_type(8)))  __bf16 bf16x8;  // MFMA A/B frag (4 VGPRs)
typedef __attribute__((ext_vector_type(16))) float  f32x16;  // 32x32 MFMA C/D frag

__device__ __forceinline__ unsigned short f2bf(float f) {
  union { float f; unsigned u; } v; v.f = f;
  unsigned r = v.u + 0x7fffu + ((v.u >> 16) & 1u);  // RNE
  return (unsigned short)(r >> 16);
}

__device__ __forceinline__ float sigmoidf(float x) { return 1.0f / (1.0f + expf(-x)); }

// ---- fused casts: x -> comb[:, :D] (stride KCOMB), Wv -> WvB, Wg -> WgB ----
#define XBLK  ((NTOK * D_DIM / 4) / 256)            // 32768
#define WVBLK ((M_DIM * D_DIM / 4) / 256)           // 1024
#define WGBLK ((D_DIM * KCOMB / 4) / 256)           // 5120
__global__ void cast_all_kernel(const float* __restrict__ x, const float* __restrict__ Wv,
                                const float* __restrict__ Wg,
                                unsigned short* __restrict__ comb,
                                unsigned short* __restrict__ WvB,
                                unsigned short* __restrict__ WgB) {
  int bid = blockIdx.x;
  const float* src; unsigned short* dst; size_t soff, doff;
  if (bid < XBLK) {
    int idx = bid * 256 + threadIdx.x;
    int n = idx >> 9;                               // D/4 = 512 quads per row
    int c = (idx & 511) << 2;
    src = x;   soff = (size_t)n * D_DIM + c;
    dst = comb; doff = (size_t)n * KCOMB + c;
  } else if (bid < XBLK + WVBLK) {
    int idx = (bid - XBLK) * 256 + threadIdx.x;
    src = Wv;  soff = (size_t)idx * 4;
    dst = WvB; doff = (size_t)idx * 4;
  } else {
    int idx = (bid - XBLK - WVBLK) * 256 + threadIdx.x;
    src = Wg;  soff = (size_t)idx * 4;
    dst = WgB; doff = (size_t)idx * 4;
  }
  float4 v = *(const float4*)(src + soff);
  ushort4 o;
  o.x = f2bf(v.x); o.y = f2bf(v.y); o.z = f2bf(v.z); o.w = f2bf(v.w);
  *(ushort4*)(dst + doff) = o;
}

// ---- scan phase 1: per-chunk affine partial  P[b][c][m] = sum_i decay^{CLEN-1-i} v[...] ----
__global__ __launch_bounds__(M_DIM) void recur_partial(
    const float* __restrict__ v, const float* __restrict__ td, float* __restrict__ P) {
  int m = threadIdx.x;
  int b = blockIdx.x >> 6;
  int c = blockIdx.x & (NCHUNK - 1);
  float decay = sigmoidf(td[m]) * 0.9f + 0.1f;
  const float* vp = v + ((size_t)(b * T_DIM + c * CLEN)) * M_DIM + m;
  float p = 0.0f;
  for (int t0 = 0; t0 < CLEN; t0 += 8) {
    float vt[8];
#pragma unroll
    for (int u = 0; u < 8; ++u) vt[u] = vp[(size_t)(t0 + u) * M_DIM];
#pragma unroll
    for (int u = 0; u < 8; ++u) p = p * decay + vt[u];
  }
  P[(size_t)blockIdx.x * M_DIM + m] = p;
}

// ---- scan phases 2+3: fold prefix partials -> chunk start state, then replay chunk ----
__global__ __launch_bounds__(M_DIM) void recur_apply(
    const float* __restrict__ v, const float* __restrict__ mem0,
    const float* __restrict__ td, const float* __restrict__ tf,
    const float* __restrict__ P,
    unsigned short* __restrict__ comb, float* __restrict__ nmem) {
  int m = threadIdx.x;
  int b = blockIdx.x >> 6;
  int c = blockIdx.x & (NCHUNK - 1);
  float decay = sigmoidf(td[m]) * 0.9f + 0.1f;
  float first = sigmoidf(tf[m]);
  float dL = decay;  // decay^64 via 6 squarings
  dL = dL * dL; dL = dL * dL; dL = dL * dL; dL = dL * dL; dL = dL * dL; dL = dL * dL;

  float s = mem0[b * M_DIM + m];
  const float* Pp = P + (size_t)(b * NCHUNK) * M_DIM + m;
  for (int ci = 0; ci < c; ++ci)
    s = s * dL + Pp[(size_t)ci * M_DIM];

  const float* vp = v + ((size_t)(b * T_DIM + c * CLEN)) * M_DIM + m;
  unsigned short* wp = comb + ((size_t)(b * T_DIM + c * CLEN)) * KCOMB + D_DIM + m;
  for (int t0 = 0; t0 < CLEN; t0 += 8) {
    float vt[8];
#pragma unroll
    for (int u = 0; u < 8; ++u) vt[u] = vp[(size_t)(t0 + u) * M_DIM];
#pragma unroll
    for (int u = 0; u < 8; ++u) {
      wp[(size_t)(t0 + u) * KCOMB] = f2bf(vt[u] + s * first);
      s = s * decay + vt[u];
    }
  }
  if (c == NCHUNK - 1) nmem[b * M_DIM + m] = s;
}

// ---- GEMM1: bf16 GEMM, C[row,col] = sum_k A[row,k]*B[col,k] (+bias[col]) ----
// 128x128 tile, BK=64, 32x32x16 MFMA, 2-phase loop. Kept for the NTOK x 512
// shape (256^2 tiling would give only 128 workgroups = half-idle GPU).
#define BM 128
#define BN 128
#define BK 64

template <bool ADD_X, int MODE>
__global__ __launch_bounds__(256) void gemm_bt(
    const unsigned short* __restrict__ A, int lda,
    const unsigned short* __restrict__ B, int ldb,
    const float* __restrict__ bias, const float* __restrict__ xadd,
    float* __restrict__ C, int N, int K) {
  const int tid = threadIdx.x;
  const int lane = tid & 63;
  const int wave = tid >> 6;
  const int wm = (wave >> 1) * 64;   // wave row offset in tile
  const int wn = (wave & 1) * 64;    // wave col offset in tile
  const int l31 = lane & 31;
  const int half = lane >> 5;

  int tileM, tileN;
  {
    int idx = blockIdx.x;
    int xcd = idx & 7, local = idx >> 3;
    if (MODE == 1) {
      tileN = (xcd * 2 + (local & 1)) * BN;
      tileM = (local >> 1) * BM;
    } else {                    // GEMM1: 128x4 tiles
      tileM = (xcd * 16 + (local >> 2)) * BM;
      tileN = (local & 3) * BN;
    }
  }

  __shared__ unsigned short As[BM * BK];  // 16 KiB
  __shared__ unsigned short Bs[BN * BK];  // 16 KiB

  f32x16 acc[2][2] = {};

  for (int k0 = 0; k0 < K; k0 += BK) {
#pragma unroll
    for (int j = 0; j < 4; ++j) {
      int c = j * 256 + tid;
      int row = c >> 3;
      int kc = c & 7;
      int gkc = kc ^ (row & 7);
      const unsigned short* gA = A + (size_t)(tileM + row) * lda + k0 + gkc * 8;
      const unsigned short* gB = B + (size_t)(tileN + row) * ldb + k0 + gkc * 8;
      __builtin_amdgcn_global_load_lds((const __attribute__((address_space(1))) void*)gA,
                                       (__attribute__((address_space(3))) void*)(As + c * 8),
                                       16, 0, 0);
      __builtin_amdgcn_global_load_lds((const __attribute__((address_space(1))) void*)gB,
                                       (__attribute__((address_space(3))) void*)(Bs + c * 8),
                                       16, 0, 0);
    }
    __syncthreads();

#pragma unroll
    for (int s = 0; s < 4; ++s) {
      const int g = s * 2 + half;
      bf16x8 af[2], bfr[2];
#pragma unroll
      for (int i = 0; i < 2; ++i) {
        int ra = wm + i * 32 + l31;
        int rb = wn + i * 32 + l31;
        af[i]  = *(const bf16x8*)(As + ra * BK + ((g ^ (ra & 7)) * 8));
        bfr[i] = *(const bf16x8*)(Bs + rb * BK + ((g ^ (rb & 7)) * 8));
      }
#pragma unroll
      for (int mi = 0; mi < 2; ++mi)
#pragma unroll
        for (int ni = 0; ni < 2; ++ni)
          acc[mi][ni] = __builtin_amdgcn_mfma_f32_32x32x16_bf16(af[mi], bfr[ni], acc[mi][ni], 0, 0, 0);
    }
    __syncthreads();
  }

#pragma unroll
  for (int mi = 0; mi < 2; ++mi) {
#pragma unroll
    for (int ni = 0; ni < 2; ++ni) {
      int col = tileN + wn + ni * 32 + l31;
      float bcol = bias[col];
#pragma unroll
      for (int r = 0; r < 16; ++r) {
        int row = tileM + wm + mi * 32 + 4 * half + (r & 3) + 8 * (r >> 2);
        float val = acc[mi][ni][r] + bcol;
        if (ADD_X) val += xadd[(size_t)row * N + col];
        C[(size_t)row * N + col] = val;
      }
    }
  }
}

// ---- GEMM2: 256x256 8-phase pipelined bf16 GEMM (guide §5 template, T1-T5) ----
// 8 waves (2Mx4N), per-wave 128x64 out = acc[4][2] of 32x32 frags. BK=64,
// double-buffered 128 KiB LDS (buf0 = even K-tile, buf1 = odd). Per phase:
// {ds_read subtile | issue one half-tile global_load_lds} -> raw s_barrier ->
// lgkmcnt(0) -> setprio(1) + 8 MFMA -> barrier. Counted vmcnt(2) ONLY at
// phases 4/8 (loads stay in flight across barriers; never drain to 0 mid-loop).
// Staging: global-side XOR (chunk ^ row&7) pre-swizzle, linear LDS dest
// (global_load_lds requirement), same-XOR on ds_read — proven scheme above.
//
// Hazard schedule (half-tile staged at phase p was last read before p's
// preceding end-barrier):
//   P1:A1(odd)  P2:B0(odd)  P3:B1(odd)   [A halves of buf0 last read P3,
//   P4:A0(ev+2) vmcnt2      P5:A1(ev+2)   B halves last read P4/P8]
//   P6:B0(ev+2) P7:B1(ev+2) P8:A0(odd+2) vmcnt2
#define BAR_FENCE() do { asm volatile("" ::: "memory"); \
  __builtin_amdgcn_s_barrier(); asm volatile("" ::: "memory"); } while (0)

template <bool ADD_X, int LDA, int LDB, int NOUT, int KTOT>
__global__ __launch_bounds__(512, 2) void gemm256_bt(
    const unsigned short* __restrict__ Amat,
    const unsigned short* __restrict__ Bmat,
    const float* __restrict__ bias,
    const float* __restrict__ xadd,
    float* __restrict__ C) {
  constexpr int NK  = KTOT / 64;          // 40 K-tiles
  constexpr int NI  = NK / 2;             // 20 iterations (2 tiles each)
  constexpr int NTN = NOUT / 256;         // 8 tile-cols
  constexpr int NWG = (NTOK / 256) * NTN; // 512 workgroups
  constexpr int PERX = NWG / 8;           // 64 per XCD

  __shared__ unsigned short As[2][256 * 64];  // 64 KiB
  __shared__ unsigned short Bs[2][256 * 64];  // 64 KiB

  const int tid  = threadIdx.x;
  const int lane = tid & 63;
  const int half = lane >> 5;
  const int l31  = lane & 31;
  const int wave = tid >> 6;
  const int wrow = (wave >> 2) * 128;   // 2 wave-rows
  const int wcol = (wave & 3) * 64;     // 4 wave-cols

  // XCD-aware swizzle (512 % 8 == 0 -> bijective). Within an XCD: 8 tile-rows
  // x all 8 tile-cols -> A panel (1.3 MB) L2-resident per row group.
  const int bid   = blockIdx.x;
  const int wgid  = (bid & 7) * PERX + (bid >> 3);
  const int tileM = (wgid / NTN) * 256;
  const int tileN = (wgid % NTN) * 256;

  // Per-thread staging source (global-side XOR pre-swizzle; row&7 invariant
  // under +64/+128 row offsets, so one base pointer serves all half-tiles).
  const int row_lo = tid >> 3;                              // 0..63
  const int scol   = (((tid & 7) ^ (row_lo & 7)) << 3);
  const unsigned short* pA = Amat + (size_t)(tileM + row_lo) * LDA + scol;
  const unsigned short* pB = Bmat + (size_t)(tileN + row_lo) * LDB + scol;

#define STAGE_A(b, h, kt) do { \
  _Pragma("unroll") for (int j = 0; j < 2; ++j) { \
    const unsigned short* _s = pA + (size_t)((h) * 128 + j * 64) * LDA + (kt) * 64; \
    __builtin_amdgcn_global_load_lds((const __attribute__((address_space(1))) void*)_s, \
        (__attribute__((address_space(3))) void*)(&As[(b)][(h) * 8192 + (j * 512 + tid) * 8]), \
        16, 0, 0); \
  } \
} while (0)

#define STAGE_B(b, h, kt) do { \
  _Pragma("unroll") for (int j = 0; j < 2; ++j) { \
    const unsigned short* _s = pB + (size_t)((h) * 128 + j * 64) * LDB + (kt) * 64; \
    __builtin_amdgcn_global_load_lds((const __attribute__((address_space(1))) void*)_s, \
        (__attribute__((address_space(3))) void*)(&Bs[(b)][(h) * 8192 + (j * 512 + tid) * 8]), \
        16, 0, 0); \
  } \
} while (0)

  f32x16 acc[4][2] = {};
  bf16x8 af[2][4];   // A subtile: 2 m-reps x 4 k-steps (reused 2 phases)
  bf16x8 bfr[4];     // B subtile: 1 n-rep  x 4 k-steps

#define READ_A(b, mh) do { \
  _Pragma("unroll") for (int mi = 0; mi < 2; ++mi) { \
    const int _r = wrow + (mh) * 64 + mi * 32 + l31; \
    _Pragma("unroll") for (int s = 0; s < 4; ++s) \
      af[mi][s] = *(const bf16x8*)(&As[(b)][_r * 64 + (((s * 2 + half) ^ (_r & 7)) << 3)]); \
  } \
} while (0)

#define READ_B(b, ni) do { \
  const int _r = wcol + (ni) * 32 + l31; \
  _Pragma("unroll") for (int s = 0; s < 4; ++s) \
    bfr[s] = *(const bf16x8*)(&Bs[(b)][_r * 64 + (((s * 2 + half) ^ (_r & 7)) << 3)]); \
} while (0)

#define MFMA_QUAD(mh, ni) do { \
  _Pragma("unroll") for (int s = 0; s < 4; ++s) \
    _Pragma("unroll") for (int mi = 0; mi < 2; ++mi) \
      acc[(mh) * 2 + mi][(ni)] = __builtin_amdgcn_mfma_f32_32x32x16_bf16( \
          af[mi][s], bfr[s], acc[(mh) * 2 + mi][(ni)], 0, 0, 0); \
} while (0)

#define PHASE_TAIL(mh, ni) do { \
  BAR_FENCE(); \
  asm volatile("s_waitcnt lgkmcnt(0)" ::: "memory"); \
  __builtin_amdgcn_s_setprio(1); \
  MFMA_QUAD(mh, ni); \
  __builtin_amdgcn_s_setprio(0); \
  BAR_FENCE(); \
} while (0)

  // Prologue: tile0 -> buf0 (8 loads) + A0 of tile1 -> buf1 (2 loads); wait
  // vmcnt(2) so tile0 is resident, A0(1) stays in flight.
  STAGE_A(0, 0, 0);
  STAGE_A(0, 1, 0);
  STAGE_B(0, 0, 0);
  STAGE_B(0, 1, 0);
  STAGE_A(1, 0, 1);
  asm volatile("s_waitcnt vmcnt(2)" ::: "memory");
  BAR_FENCE();

#define ITER8(KE, FULL) do { \
  /* P1: even quad(0,0) */ \
  READ_A(0, 0); READ_B(0, 0); \
  STAGE_A(1, 1, (KE) + 1); \
  asm volatile("s_waitcnt lgkmcnt(8)" ::: "memory"); \
  PHASE_TAIL(0, 0); \
  /* P2: even quad(0,1) */ \
  READ_B(0, 1); \
  STAGE_B(1, 0, (KE) + 1); \
  PHASE_TAIL(0, 1); \
  /* P3: even quad(1,1) */ \
  READ_A(0, 1); \
  STAGE_B(1, 1, (KE) + 1); \
  PHASE_TAIL(1, 1); \
  /* P4: even quad(1,0); gate buf1 (odd tile) */ \
  READ_B(0, 0); \
  if (FULL) { STAGE_A(0, 0, (KE) + 2); \
              asm volatile("s_waitcnt vmcnt(2)" ::: "memory"); } \
  else      { asm volatile("s_waitcnt vmcnt(0)" ::: "memory"); } \
  PHASE_TAIL(1, 0); \
  /* P5: odd quad(0,0) */ \
  READ_A(1, 0); READ_B(1, 0); \
  if (FULL) STAGE_A(0, 1, (KE) + 2); \
  asm volatile("s_waitcnt lgkmcnt(8)" ::: "memory"); \
  PHASE_TAIL(0, 0); \
  /* P6: odd quad(0,1) */ \
  READ_B(1, 1); \
  if (FULL) STAGE_B(0, 0, (KE) + 2); \
  PHASE_TAIL(0, 1); \
  /* P7: odd quad(1,1) */ \
  READ_A(1, 1); \
  if (FULL) STAGE_B(0, 1, (KE) + 2); \
  PHASE_TAIL(1, 1); \
  /* P8: odd quad(1,0); gate buf0 (next even tile) */ \
  READ_B(1, 0); \
  if (FULL) { STAGE_A(1, 0, (KE) + 3); \
              asm volatile("s_waitcnt vmcnt(2)" ::: "memory"); } \
  PHASE_TAIL(1, 0); \
} while (0)

#pragma unroll 1
  for (int i = 0; i < NI - 1; ++i) ITER8(2 * i, 1);
  ITER8(2 * (NI - 1), 0);   // last iteration: no prefetch, drain at P4

#undef ITER8
#undef PHASE_TAIL
#undef MFMA_QUAD
#undef READ_B
#undef READ_A
#undef STAGE_B
#undef STAGE_A

  // Epilogue: 32x32 C/D layout col=lane&31, row=(r&3)+8*(r>>2)+4*(lane>>5).
#pragma unroll
  for (int mq = 0; mq < 4; ++mq) {
#pragma unroll
    for (int ni = 0; ni < 2; ++ni) {
      const int col = tileN + wcol + ni * 32 + l31;
      const float bc = bias[col];
#pragma unroll
      for (int r = 0; r < 16; ++r) {
        const int row = tileM + wrow + mq * 32 + 4 * half + (r & 3) + 8 * (r >> 2);
        float val = acc[mq][ni][r] + bc;
        if (ADD_X) val += xadd[(size_t)row * NOUT + col];
        C[(size_t)row * NOUT + col] = val;
      }
    }
  }
}

extern "C" void kernel_launch(void* const* d_in, const int* in_sizes, int n_in,
                              void* d_out, int out_size, void* d_ws, size_t ws_size,
                              hipStream_t stream) {
  const float* x   = (const float*)d_in[0];
  const float* mem = (const float*)d_in[1];
  const float* Wv  = (const float*)d_in[2];
  const float* bv  = (const float*)d_in[3];
  const float* Wg  = (const float*)d_in[4];
  const float* bg  = (const float*)d_in[5];
  const float* td  = (const float*)d_in[6];
  const float* tf  = (const float*)d_in[7];
  float* out = (float*)d_out;  // [NTOK, D] output, then [B*M] next_memory

  // Workspace layout
  char* ws = (char*)d_ws;
  unsigned short* comb = (unsigned short*)ws;                              // [NTOK, KCOMB] bf16
  float* v = (float*)(ws + (size_t)NTOK * KCOMB * 2);                      // [NTOK, M] fp32
  unsigned short* WvB = (unsigned short*)((char*)v + (size_t)NTOK * M_DIM * 4);   // [M, D] bf16
  unsigned short* WgB = (unsigned short*)((char*)WvB + (size_t)M_DIM * D_DIM * 2); // [D, KCOMB] bf16
  float* P = (float*)WvB;  // aliases WvB (dead after GEMM1); P is 512 KB

  // 1. fused casts
  cast_all_kernel<<<XBLK + WVBLK + WGBLK, 256, 0, stream>>>(x, Wv, Wg, comb, WvB, WgB);

  // 2. v = x_bf16 . Wv^T + bv   (A = combined[:, :D] via lda=KCOMB)
  gemm_bt<false, 0><<<(NTOK / BM) * (M_DIM / BN), 256, 0, stream>>>(
      comb, KCOMB, WvB, D_DIM, bv, nullptr, v, M_DIM, D_DIM);

  // 3. parallel scan: chunk partials, then prefix-fold + replay
  recur_partial<<<B_DIM * NCHUNK, M_DIM, 0, stream>>>(v, td, P);
  recur_apply<<<B_DIM * NCHUNK, M_DIM, 0, stream>>>(
      v, mem, td, tf, P, comb, out + (size_t)NTOK * D_DIM);

  // 4. out = x + combined . Wg^T + bg   (256^2 8-phase kernel)
  gemm256_bt<true, KCOMB, KCOMB, D_DIM, KCOMB>
      <<<(NTOK / 256) * (D_DIM / 256), 512, 0, stream>>>(comb, WgB, bg, x, out);
}

// Round 2
// 508.718 us; speedup vs baseline: 1.0442x; 1.0071x over previous
//
#include <hip/hip_runtime.h>
#include <hip/hip_bf16.h>
#include <cstdint>
#include <cstddef>

// Problem dims (fixed by reference)
#define B_DIM 4
#define T_DIM 4096
#define D_DIM 2048
#define M_DIM 512
#define NTOK  (B_DIM * T_DIM)     // 16384 rows
#define KCOMB (D_DIM + M_DIM)     // 2560
#define NCHUNK 64                 // chunks per chain for the parallel scan
#define CLEN   64                 // T / NCHUNK

typedef __attribute__((ext_vector_type(8)))  __bf16 bf16x8;  // MFMA A/B frag (4 VGPRs)
typedef __attribute__((ext_vector_type(16))) float  f32x16;  // 32x32 MFMA C/D frag

__device__ __forceinline__ unsigned short f2bf(float f) {
  union { float f; unsigned u; } v; v.f = f;
  unsigned r = v.u + 0x7fffu + ((v.u >> 16) & 1u);  // RNE
  return (unsigned short)(r >> 16);
}

__device__ __forceinline__ float sigmoidf(float x) { return 1.0f / (1.0f + expf(-x)); }

// ---- fused casts: x -> comb[:, :D] (stride KCOMB), Wv -> WvB, Wg -> WgB ----
#define XBLK  ((NTOK * D_DIM / 4) / 256)            // 32768
#define WVBLK ((M_DIM * D_DIM / 4) / 256)           // 1024
#define WGBLK ((D_DIM * KCOMB / 4) / 256)           // 5120
__global__ void cast_all_kernel(const float* __restrict__ x, const float* __restrict__ Wv,
                                const float* __restrict__ Wg,
                                unsigned short* __restrict__ comb,
                                unsigned short* __restrict__ WvB,
                                unsigned short* __restrict__ WgB) {
  int bid = blockIdx.x;
  const float* src; unsigned short* dst; size_t soff, doff;
  if (bid < XBLK) {
    int idx = bid * 256 + threadIdx.x;
    int n = idx >> 9;                               // D/4 = 512 quads per row
    int c = (idx & 511) << 2;
    src = x;   soff = (size_t)n * D_DIM + c;
    dst = comb; doff = (size_t)n * KCOMB + c;
  } else if (bid < XBLK + WVBLK) {
    int idx = (bid - XBLK) * 256 + threadIdx.x;
    src = Wv;  soff = (size_t)idx * 4;
    dst = WvB; doff = (size_t)idx * 4;
  } else {
    int idx = (bid - XBLK - WVBLK) * 256 + threadIdx.x;
    src = Wg;  soff = (size_t)idx * 4;
    dst = WgB; doff = (size_t)idx * 4;
  }
  float4 v = *(const float4*)(src + soff);
  ushort4 o;
  o.x = f2bf(v.x); o.y = f2bf(v.y); o.z = f2bf(v.z); o.w = f2bf(v.w);
  *(ushort4*)(dst + doff) = o;
}

// ---- scan phase 1: per-chunk affine partial  P[b][c][m] = sum_i decay^{CLEN-1-i} v[...] ----
__global__ __launch_bounds__(M_DIM) void recur_partial(
    const float* __restrict__ v, const float* __restrict__ td, float* __restrict__ P) {
  int m = threadIdx.x;
  int b = blockIdx.x >> 6;
  int c = blockIdx.x & (NCHUNK - 1);
  float decay = sigmoidf(td[m]) * 0.9f + 0.1f;
  const float* vp = v + ((size_t)(b * T_DIM + c * CLEN)) * M_DIM + m;
  float p = 0.0f;
  for (int t0 = 0; t0 < CLEN; t0 += 8) {
    float vt[8];
#pragma unroll
    for (int u = 0; u < 8; ++u) vt[u] = vp[(size_t)(t0 + u) * M_DIM];
#pragma unroll
    for (int u = 0; u < 8; ++u) p = p * decay + vt[u];
  }
  P[(size_t)blockIdx.x * M_DIM + m] = p;
}

// ---- scan phases 2+3: fold prefix partials -> chunk start state, then replay chunk ----
__global__ __launch_bounds__(M_DIM) void recur_apply(
    const float* __restrict__ v, const float* __restrict__ mem0,
    const float* __restrict__ td, const float* __restrict__ tf,
    const float* __restrict__ P,
    unsigned short* __restrict__ comb, float* __restrict__ nmem) {
  int m = threadIdx.x;
  int b = blockIdx.x >> 6;
  int c = blockIdx.x & (NCHUNK - 1);
  float decay = sigmoidf(td[m]) * 0.9f + 0.1f;
  float first = sigmoidf(tf[m]);
  float dL = decay;  // decay^64 via 6 squarings
  dL = dL * dL; dL = dL * dL; dL = dL * dL; dL = dL * dL; dL = dL * dL; dL = dL * dL;

  float s = mem0[b * M_DIM + m];
  const float* Pp = P + (size_t)(b * NCHUNK) * M_DIM + m;
  for (int ci = 0; ci < c; ++ci)
    s = s * dL + Pp[(size_t)ci * M_DIM];

  const float* vp = v + ((size_t)(b * T_DIM + c * CLEN)) * M_DIM + m;
  unsigned short* wp = comb + ((size_t)(b * T_DIM + c * CLEN)) * KCOMB + D_DIM + m;
  for (int t0 = 0; t0 < CLEN; t0 += 8) {
    float vt[8];
#pragma unroll
    for (int u = 0; u < 8; ++u) vt[u] = vp[(size_t)(t0 + u) * M_DIM];
#pragma unroll
    for (int u = 0; u < 8; ++u) {
      wp[(size_t)(t0 + u) * KCOMB] = f2bf(vt[u] + s * first);
      s = s * decay + vt[u];
    }
  }
  if (c == NCHUNK - 1) nmem[b * M_DIM + m] = s;
}

// ---- GEMM1: bf16 GEMM, C[row,col] = sum_k A[row,k]*B[col,k] (+bias[col]) ----
// 128x128 tile, BK=64, 32x32x16 MFMA, 2-phase loop. Kept for the NTOK x 512
// shape (256^2 tiling would give only 128 workgroups = half-idle GPU).
#define BM 128
#define BN 128
#define BK 64

template <bool ADD_X, int MODE>
__global__ __launch_bounds__(256) void gemm_bt(
    const unsigned short* __restrict__ A, int lda,
    const unsigned short* __restrict__ B, int ldb,
    const float* __restrict__ bias, const float* __restrict__ xadd,
    float* __restrict__ C, int N, int K) {
  const int tid = threadIdx.x;
  const int lane = tid & 63;
  const int wave = tid >> 6;
  const int wm = (wave >> 1) * 64;   // wave row offset in tile
  const int wn = (wave & 1) * 64;    // wave col offset in tile
  const int l31 = lane & 31;
  const int half = lane >> 5;

  int tileM, tileN;
  {
    int idx = blockIdx.x;
    int xcd = idx & 7, local = idx >> 3;
    if (MODE == 1) {
      tileN = (xcd * 2 + (local & 1)) * BN;
      tileM = (local >> 1) * BM;
    } else {                    // GEMM1: 128x4 tiles
      tileM = (xcd * 16 + (local >> 2)) * BM;
      tileN = (local & 3) * BN;
    }
  }

  __shared__ unsigned short As[BM * BK];  // 16 KiB
  __shared__ unsigned short Bs[BN * BK];  // 16 KiB

  f32x16 acc[2][2] = {};

  for (int k0 = 0; k0 < K; k0 += BK) {
#pragma unroll
    for (int j = 0; j < 4; ++j) {
      int c = j * 256 + tid;
      int row = c >> 3;
      int kc = c & 7;
      int gkc = kc ^ (row & 7);
      const unsigned short* gA = A + (size_t)(tileM + row) * lda + k0 + gkc * 8;
      const unsigned short* gB = B + (size_t)(tileN + row) * ldb + k0 + gkc * 8;
      __builtin_amdgcn_global_load_lds((const __attribute__((address_space(1))) void*)gA,
                                       (__attribute__((address_space(3))) void*)(As + c * 8),
                                       16, 0, 0);
      __builtin_amdgcn_global_load_lds((const __attribute__((address_space(1))) void*)gB,
                                       (__attribute__((address_space(3))) void*)(Bs + c * 8),
                                       16, 0, 0);
    }
    __syncthreads();

#pragma unroll
    for (int s = 0; s < 4; ++s) {
      const int g = s * 2 + half;
      bf16x8 af[2], bfr[2];
#pragma unroll
      for (int i = 0; i < 2; ++i) {
        int ra = wm + i * 32 + l31;
        int rb = wn + i * 32 + l31;
        af[i]  = *(const bf16x8*)(As + ra * BK + ((g ^ (ra & 7)) * 8));
        bfr[i] = *(const bf16x8*)(Bs + rb * BK + ((g ^ (rb & 7)) * 8));
      }
#pragma unroll
      for (int mi = 0; mi < 2; ++mi)
#pragma unroll
        for (int ni = 0; ni < 2; ++ni)
          acc[mi][ni] = __builtin_amdgcn_mfma_f32_32x32x16_bf16(af[mi], bfr[ni], acc[mi][ni], 0, 0, 0);
    }
    __syncthreads();
  }

#pragma unroll
  for (int mi = 0; mi < 2; ++mi) {
#pragma unroll
    for (int ni = 0; ni < 2; ++ni) {
      int col = tileN + wn + ni * 32 + l31;
      float bcol = bias[col];
#pragma unroll
      for (int r = 0; r < 16; ++r) {
        int row = tileM + wm + mi * 32 + 4 * half + (r & 3) + 8 * (r >> 2);
        float val = acc[mi][ni][r] + bcol;
        if (ADD_X) val += xadd[(size_t)row * N + col];
        C[(size_t)row * N + col] = val;
      }
    }
  }
}

// ---- GEMM2: 256x256 8-phase pipelined bf16 GEMM, v2 (re-timed prefetch) ----
// 8 waves (2Mx4N), per-wave 128x64 out = acc[4][2] of 32x32 frags. BK=64,
// double-buffered 128 KiB LDS. Per phase: {ds_read subtile | stage issues}
// -> s_barrier -> lgkmcnt(0)+sched_barrier -> setprio(1) + 8 MFMA (4 indep
// (mi,ni) chains x depth 2) -> barrier.
//
// v2 change vs v1: stages are issued at the EARLIEST legal point after each
// LDS region's last read (A halves last read P3/P7, B halves last read P4/P8
// due to sp0 re-read), giving every load >=3 phases issue->gate slack instead
// of 1. Steady-state queue at each gate = 12 loads -> vmcnt(4).
//
// Steady state, iteration i (tiles 2i in buf0, 2i+1 in buf1):
//   P1: read A(b0,mh0)+B(b0,sp0); stage B(b1)<-tile 2i+1;  quad(0,0)
//   P2: read B(b0,sp1);                                    quad(0,1)
//   P3: read A(b0,mh1);                                    quad(1,1)
//   P4: read B(b0,sp0); stage A(b0)<-2i+2; vmcnt(4);       quad(1,0)
//   P5: read A(b1,mh0)+B(b1,sp0); stage B(b0)<-2i+2;       quad(0,0)
//   P6: read B(b1,sp1);                                    quad(0,1)
//   P7: read A(b1,mh1);                                    quad(1,1)
//   P8: read B(b1,sp0); stage A(b1)<-2i+3; vmcnt(4);       quad(1,0)
// Gate P4 completes {A(b1,2i+1) [prev P8], B(b1,2i+1) [P1]}; gate P8
// completes {A(b0,2i+2) [P4], B(b0,2i+2) [P5]}. Min slack 3 phases.
#define BAR_FENCE() do { asm volatile("" ::: "memory"); \
  __builtin_amdgcn_s_barrier(); asm volatile("" ::: "memory"); } while (0)

template <bool ADD_X, int LDA, int LDB, int NOUT, int KTOT>
__global__ __launch_bounds__(512, 2) void gemm256_bt(
    const unsigned short* __restrict__ Amat,
    const unsigned short* __restrict__ Bmat,
    const float* __restrict__ bias,
    const float* __restrict__ xadd,
    float* __restrict__ C) {
  constexpr int NK  = KTOT / 64;          // 40 K-tiles
  constexpr int NI  = NK / 2;             // 20 iterations (2 tiles each)
  constexpr int NTN = NOUT / 256;         // 8 tile-cols
  constexpr int NWG = (NTOK / 256) * NTN; // 512 workgroups
  constexpr int PERX = NWG / 8;           // 64 per XCD

  __shared__ unsigned short As[2][256 * 64];  // 64 KiB
  __shared__ unsigned short Bs[2][256 * 64];  // 64 KiB

  const int tid  = threadIdx.x;
  const int lane = tid & 63;
  const int half = lane >> 5;
  const int l31  = lane & 31;
  const int wave = tid >> 6;
  const int wrow = (wave >> 2) * 128;   // 2 wave-rows
  const int wcol = (wave & 3) * 64;     // 4 wave-cols

  // XCD-aware swizzle (512 % 8 == 0 -> bijective).
  const int bid   = blockIdx.x;
  const int wgid  = (bid & 7) * PERX + (bid >> 3);
  const int tileM = (wgid / NTN) * 256;
  const int tileN = (wgid % NTN) * 256;

  // Per-thread staging source (global-side XOR pre-swizzle; row&7 invariant
  // under +64/+128 row offsets, so one base pointer serves all half-tiles).
  const int row_lo = tid >> 3;                              // 0..63
  const int scol   = (((tid & 7) ^ (row_lo & 7)) << 3);
  const unsigned short* pA = Amat + (size_t)(tileM + row_lo) * LDA + scol;
  const unsigned short* pB = Bmat + (size_t)(tileN + row_lo) * LDB + scol;

#define STAGE_A(b, h, kt) do { \
  _Pragma("unroll") for (int j = 0; j < 2; ++j) { \
    const unsigned short* _s = pA + (size_t)((h) * 128 + j * 64) * LDA + (kt) * 64; \
    __builtin_amdgcn_global_load_lds((const __attribute__((address_space(1))) void*)_s, \
        (__attribute__((address_space(3))) void*)(&As[(b)][(h) * 8192 + (j * 512 + tid) * 8]), \
        16, 0, 0); \
  } \
} while (0)

#define STAGE_B(b, h, kt) do { \
  _Pragma("unroll") for (int j = 0; j < 2; ++j) { \
    const unsigned short* _s = pB + (size_t)((h) * 128 + j * 64) * LDB + (kt) * 64; \
    __builtin_amdgcn_global_load_lds((const __attribute__((address_space(1))) void*)_s, \
        (__attribute__((address_space(3))) void*)(&Bs[(b)][(h) * 8192 + (j * 512 + tid) * 8]), \
        16, 0, 0); \
  } \
} while (0)

  f32x16 acc[4][2] = {};
  bf16x8 af[2][4];   // A subtile: 2 m-reps x 4 k-steps (one mh at a time)
  bf16x8 bfr[2][2];  // B subtile: 2 n-reps x 2 k-steps (one s-pair at a time)

#define READ_A(b, mh) do { \
  _Pragma("unroll") for (int mi = 0; mi < 2; ++mi) { \
    const int _r = wrow + (mh) * 64 + mi * 32 + l31; \
    _Pragma("unroll") for (int s = 0; s < 4; ++s) \
      af[mi][s] = *(const bf16x8*)(&As[(b)][_r * 64 + (((s * 2 + half) ^ (_r & 7)) << 3)]); \
  } \
} while (0)

#define READ_BSP(b, sp) do { \
  _Pragma("unroll") for (int ni = 0; ni < 2; ++ni) { \
    const int _r = wcol + ni * 32 + l31; \
    _Pragma("unroll") for (int j = 0; j < 2; ++j) \
      bfr[ni][j] = *(const bf16x8*)(&Bs[(b)][_r * 64 + \
          (((((sp) * 2 + j) * 2 + half) ^ (_r & 7)) << 3)]); \
  } \
} while (0)

// 8 MFMA: 4 independent (mi,ni) chains x depth 2 (j)
#define MFMA_Q(mh, sp) do { \
  _Pragma("unroll") for (int j = 0; j < 2; ++j) \
    _Pragma("unroll") for (int mi = 0; mi < 2; ++mi) \
      _Pragma("unroll") for (int ni = 0; ni < 2; ++ni) \
        acc[(mh) * 2 + mi][(ni)] = __builtin_amdgcn_mfma_f32_32x32x16_bf16( \
            af[mi][(sp) * 2 + j], bfr[ni][j], acc[(mh) * 2 + mi][(ni)], 0, 0, 0); \
} while (0)

#define PHASE_TAIL(mh, sp) do { \
  BAR_FENCE(); \
  asm volatile("s_waitcnt lgkmcnt(0)" ::: "memory"); \
  __builtin_amdgcn_sched_barrier(0); \
  __builtin_amdgcn_s_setprio(1); \
  MFMA_Q(mh, sp); \
  __builtin_amdgcn_s_setprio(0); \
  BAR_FENCE(); \
} while (0)

  // Prologue: buf0 <- tile0 (8 loads), buf1 <- A halves of tile1 (4 loads);
  // vmcnt(4) = buf0 resident, A(b1,1) stays in flight (B(b1,1) staged at P1).
  STAGE_A(0, 0, 0); STAGE_A(0, 1, 0);
  STAGE_B(0, 0, 0); STAGE_B(0, 1, 0);
  STAGE_A(1, 0, 1); STAGE_A(1, 1, 1);
  asm volatile("s_waitcnt vmcnt(4)" ::: "memory");
  BAR_FENCE();

#define ITER(i2, FULL) do { \
  /* P1 */ \
  READ_A(0, 0); READ_BSP(0, 0); \
  STAGE_B(1, 0, (i2) + 1); STAGE_B(1, 1, (i2) + 1); \
  PHASE_TAIL(0, 0); \
  /* P2 */ \
  READ_BSP(0, 1); \
  PHASE_TAIL(0, 1); \
  /* P3 */ \
  READ_A(0, 1); \
  PHASE_TAIL(1, 1); \
  /* P4: gate buf1 (tile i2+1) */ \
  READ_BSP(0, 0); \
  if (FULL) { STAGE_A(0, 0, (i2) + 2); STAGE_A(0, 1, (i2) + 2); \
              asm volatile("s_waitcnt vmcnt(4)" ::: "memory"); } \
  else      { asm volatile("s_waitcnt vmcnt(0)" ::: "memory"); } \
  PHASE_TAIL(1, 0); \
  /* P5 */ \
  READ_A(1, 0); READ_BSP(1, 0); \
  if (FULL) { STAGE_B(0, 0, (i2) + 2); STAGE_B(0, 1, (i2) + 2); } \
  PHASE_TAIL(0, 0); \
  /* P6 */ \
  READ_BSP(1, 1); \
  PHASE_TAIL(0, 1); \
  /* P7 */ \
  READ_A(1, 1); \
  PHASE_TAIL(1, 1); \
  /* P8: gate buf0 (tile i2+2) */ \
  READ_BSP(1, 0); \
  if (FULL) { STAGE_A(1, 0, (i2) + 3); STAGE_A(1, 1, (i2) + 3); \
              asm volatile("s_waitcnt vmcnt(4)" ::: "memory"); } \
  PHASE_TAIL(1, 0); \
} while (0)

#pragma unroll 1
  for (int i = 0; i < NI - 1; ++i) ITER(2 * i, 1);
  ITER(2 * (NI - 1), 0);   // last iteration: no new stages; P4 drains

#undef ITER
#undef PHASE_TAIL
#undef MFMA_Q
#undef READ_BSP
#undef READ_A
#undef STAGE_B
#undef STAGE_A

  // Epilogue: 32x32 C/D layout col=lane&31, row=(r&3)+8*(r>>2)+4*(lane>>5).
#pragma unroll
  for (int mq = 0; mq < 4; ++mq) {
#pragma unroll
    for (int ni = 0; ni < 2; ++ni) {
      const int col = tileN + wcol + ni * 32 + l31;
      const float bc = bias[col];
#pragma unroll
      for (int r = 0; r < 16; ++r) {
        const int row = tileM + wrow + mq * 32 + 4 * half + (r & 3) + 8 * (r >> 2);
        float val = acc[mq][ni][r] + bc;
        if (ADD_X) val += xadd[(size_t)row * NOUT + col];
        C[(size_t)row * NOUT + col] = val;
      }
    }
  }
}

extern "C" void kernel_launch(void* const* d_in, const int* in_sizes, int n_in,
                              void* d_out, int out_size, void* d_ws, size_t ws_size,
                              hipStream_t stream) {
  const float* x   = (const float*)d_in[0];
  const float* mem = (const float*)d_in[1];
  const float* Wv  = (const float*)d_in[2];
  const float* bv  = (const float*)d_in[3];
  const float* Wg  = (const float*)d_in[4];
  const float* bg  = (const float*)d_in[5];
  const float* td  = (const float*)d_in[6];
  const float* tf  = (const float*)d_in[7];
  float* out = (float*)d_out;  // [NTOK, D] output, then [B*M] next_memory

  // Workspace layout
  char* ws = (char*)d_ws;
  unsigned short* comb = (unsigned short*)ws;                              // [NTOK, KCOMB] bf16
  float* v = (float*)(ws + (size_t)NTOK * KCOMB * 2);                      // [NTOK, M] fp32
  unsigned short* WvB = (unsigned short*)((char*)v + (size_t)NTOK * M_DIM * 4);   // [M, D] bf16
  unsigned short* WgB = (unsigned short*)((char*)WvB + (size_t)M_DIM * D_DIM * 2); // [D, KCOMB] bf16
  float* P = (float*)WvB;  // aliases WvB (dead after GEMM1); P is 512 KB

  // 1. fused casts
  cast_all_kernel<<<XBLK + WVBLK + WGBLK, 256, 0, stream>>>(x, Wv, Wg, comb, WvB, WgB);

  // 2. v = x_bf16 . Wv^T + bv   (A = combined[:, :D] via lda=KCOMB)
  gemm_bt<false, 0><<<(NTOK / BM) * (M_DIM / BN), 256, 0, stream>>>(
      comb, KCOMB, WvB, D_DIM, bv, nullptr, v, M_DIM, D_DIM);

  // 3. parallel scan: chunk partials, then prefix-fold + replay
  recur_partial<<<B_DIM * NCHUNK, M_DIM, 0, stream>>>(v, td, P);
  recur_apply<<<B_DIM * NCHUNK, M_DIM, 0, stream>>>(
      v, mem, td, tf, P, comb, out + (size_t)NTOK * D_DIM);

  // 4. out = x + combined . Wg^T + bg   (256^2 8-phase kernel, v2 schedule)
  gemm256_bt<true, KCOMB, KCOMB, D_DIM, KCOMB>
      <<<(NTOK / 256) * (D_DIM / 256), 512, 0, stream>>>(comb, WgB, bg, x, out);
}

// Round 4
// 508.149 us; speedup vs baseline: 1.0454x; 1.0011x over previous
//
#include <hip/hip_runtime.h>
#include <hip/hip_bf16.h>
#include <cstdint>
#include <cstddef>

// Problem dims (fixed by reference)
#define B_DIM 4
#define T_DIM 4096
#define D_DIM 2048
#define M_DIM 512
#define NTOK  (B_DIM * T_DIM)     // 16384 rows
#define KCOMB (D_DIM + M_DIM)     // 2560
#define NCHUNK 64                 // chunks per chain for the parallel scan
#define CLEN   64                 // T / NCHUNK

typedef __attribute__((ext_vector_type(8)))  __bf16 bf16x8;  // MFMA A/B frag (4 VGPRs)
typedef __attribute__((ext_vector_type(16))) float  f32x16;  // 32x32 MFMA C/D frag
typedef __attribute__((ext_vector_type(4)))  float  f32x4;   // 16x16 MFMA C/D frag

__device__ __forceinline__ unsigned short f2bf(float f) {
  union { float f; unsigned u; } v; v.f = f;
  unsigned r = v.u + 0x7fffu + ((v.u >> 16) & 1u);  // RNE
  return (unsigned short)(r >> 16);
}

__device__ __forceinline__ float sigmoidf(float x) { return 1.0f / (1.0f + expf(-x)); }

// ---- fused casts: x -> comb[:, :D] (stride KCOMB), Wv -> WvB, Wg -> WgB ----
#define XBLK  ((NTOK * D_DIM / 4) / 256)            // 32768
#define WVBLK ((M_DIM * D_DIM / 4) / 256)           // 1024
#define WGBLK ((D_DIM * KCOMB / 4) / 256)           // 5120
__global__ void cast_all_kernel(const float* __restrict__ x, const float* __restrict__ Wv,
                                const float* __restrict__ Wg,
                                unsigned short* __restrict__ comb,
                                unsigned short* __restrict__ WvB,
                                unsigned short* __restrict__ WgB) {
  int bid = blockIdx.x;
  const float* src; unsigned short* dst; size_t soff, doff;
  if (bid < XBLK) {
    int idx = bid * 256 + threadIdx.x;
    int n = idx >> 9;                               // D/4 = 512 quads per row
    int c = (idx & 511) << 2;
    src = x;   soff = (size_t)n * D_DIM + c;
    dst = comb; doff = (size_t)n * KCOMB + c;
  } else if (bid < XBLK + WVBLK) {
    int idx = (bid - XBLK) * 256 + threadIdx.x;
    src = Wv;  soff = (size_t)idx * 4;
    dst = WvB; doff = (size_t)idx * 4;
  } else {
    int idx = (bid - XBLK - WVBLK) * 256 + threadIdx.x;
    src = Wg;  soff = (size_t)idx * 4;
    dst = WgB; doff = (size_t)idx * 4;
  }
  float4 v = *(const float4*)(src + soff);
  ushort4 o;
  o.x = f2bf(v.x); o.y = f2bf(v.y); o.z = f2bf(v.z); o.w = f2bf(v.w);
  *(ushort4*)(dst + doff) = o;
}

// ---- scan phase 1: per-chunk affine partial  P[b][c][m] = sum_i decay^{CLEN-1-i} v[...] ----
__global__ __launch_bounds__(M_DIM) void recur_partial(
    const float* __restrict__ v, const float* __restrict__ td, float* __restrict__ P) {
  int m = threadIdx.x;
  int b = blockIdx.x >> 6;
  int c = blockIdx.x & (NCHUNK - 1);
  float decay = sigmoidf(td[m]) * 0.9f + 0.1f;
  const float* vp = v + ((size_t)(b * T_DIM + c * CLEN)) * M_DIM + m;
  float p = 0.0f;
  for (int t0 = 0; t0 < CLEN; t0 += 8) {
    float vt[8];
#pragma unroll
    for (int u = 0; u < 8; ++u) vt[u] = vp[(size_t)(t0 + u) * M_DIM];
#pragma unroll
    for (int u = 0; u < 8; ++u) p = p * decay + vt[u];
  }
  P[(size_t)blockIdx.x * M_DIM + m] = p;
}

// ---- scan phases 2+3: fold prefix partials -> chunk start state, then replay chunk ----
__global__ __launch_bounds__(M_DIM) void recur_apply(
    const float* __restrict__ v, const float* __restrict__ mem0,
    const float* __restrict__ td, const float* __restrict__ tf,
    const float* __restrict__ P,
    unsigned short* __restrict__ comb, float* __restrict__ nmem) {
  int m = threadIdx.x;
  int b = blockIdx.x >> 6;
  int c = blockIdx.x & (NCHUNK - 1);
  float decay = sigmoidf(td[m]) * 0.9f + 0.1f;
  float first = sigmoidf(tf[m]);
  float dL = decay;  // decay^64 via 6 squarings
  dL = dL * dL; dL = dL * dL; dL = dL * dL; dL = dL * dL; dL = dL * dL; dL = dL * dL;

  float s = mem0[b * M_DIM + m];
  const float* Pp = P + (size_t)(b * NCHUNK) * M_DIM + m;
  for (int ci = 0; ci < c; ++ci)
    s = s * dL + Pp[(size_t)ci * M_DIM];

  const float* vp = v + ((size_t)(b * T_DIM + c * CLEN)) * M_DIM + m;
  unsigned short* wp = comb + ((size_t)(b * T_DIM + c * CLEN)) * KCOMB + D_DIM + m;
  for (int t0 = 0; t0 < CLEN; t0 += 8) {
    float vt[8];
#pragma unroll
    for (int u = 0; u < 8; ++u) vt[u] = vp[(size_t)(t0 + u) * M_DIM];
#pragma unroll
    for (int u = 0; u < 8; ++u) {
      wp[(size_t)(t0 + u) * KCOMB] = f2bf(vt[u] + s * first);
      s = s * decay + vt[u];
    }
  }
  if (c == NCHUNK - 1) nmem[b * M_DIM + m] = s;
}

// ---- GEMM1: bf16 GEMM, C[row,col] = sum_k A[row,k]*B[col,k] (+bias[col]) ----
// 128x128 tile, BK=64, 32x32x16 MFMA, 2-phase loop. Kept for the NTOK x 512
// shape (256^2 tiling would give only 128 workgroups = half-idle GPU).
#define BM 128
#define BN 128
#define BK 64

template <bool ADD_X, int MODE>
__global__ __launch_bounds__(256) void gemm_bt(
    const unsigned short* __restrict__ A, int lda,
    const unsigned short* __restrict__ B, int ldb,
    const float* __restrict__ bias, const float* __restrict__ xadd,
    float* __restrict__ C, int N, int K) {
  const int tid = threadIdx.x;
  const int lane = tid & 63;
  const int wave = tid >> 6;
  const int wm = (wave >> 1) * 64;   // wave row offset in tile
  const int wn = (wave & 1) * 64;    // wave col offset in tile
  const int l31 = lane & 31;
  const int half = lane >> 5;

  int tileM, tileN;
  {
    int idx = blockIdx.x;
    int xcd = idx & 7, local = idx >> 3;
    if (MODE == 1) {
      tileN = (xcd * 2 + (local & 1)) * BN;
      tileM = (local >> 1) * BM;
    } else {                    // GEMM1: 128x4 tiles
      tileM = (xcd * 16 + (local >> 2)) * BM;
      tileN = (local & 3) * BN;
    }
  }

  __shared__ unsigned short As[BM * BK];  // 16 KiB
  __shared__ unsigned short Bs[BN * BK];  // 16 KiB

  f32x16 acc[2][2] = {};

  for (int k0 = 0; k0 < K; k0 += BK) {
#pragma unroll
    for (int j = 0; j < 4; ++j) {
      int c = j * 256 + tid;
      int row = c >> 3;
      int kc = c & 7;
      int gkc = kc ^ (row & 7);
      const unsigned short* gA = A + (size_t)(tileM + row) * lda + k0 + gkc * 8;
      const unsigned short* gB = B + (size_t)(tileN + row) * ldb + k0 + gkc * 8;
      __builtin_amdgcn_global_load_lds((const __attribute__((address_space(1))) void*)gA,
                                       (__attribute__((address_space(3))) void*)(As + c * 8),
                                       16, 0, 0);
      __builtin_amdgcn_global_load_lds((const __attribute__((address_space(1))) void*)gB,
                                       (__attribute__((address_space(3))) void*)(Bs + c * 8),
                                       16, 0, 0);
    }
    __syncthreads();

#pragma unroll
    for (int s = 0; s < 4; ++s) {
      const int g = s * 2 + half;
      bf16x8 af[2], bfr[2];
#pragma unroll
      for (int i = 0; i < 2; ++i) {
        int ra = wm + i * 32 + l31;
        int rb = wn + i * 32 + l31;
        af[i]  = *(const bf16x8*)(As + ra * BK + ((g ^ (ra & 7)) * 8));
        bfr[i] = *(const bf16x8*)(Bs + rb * BK + ((g ^ (rb & 7)) * 8));
      }
#pragma unroll
      for (int mi = 0; mi < 2; ++mi)
#pragma unroll
        for (int ni = 0; ni < 2; ++ni)
          acc[mi][ni] = __builtin_amdgcn_mfma_f32_32x32x16_bf16(af[mi], bfr[ni], acc[mi][ni], 0, 0, 0);
    }
    __syncthreads();
  }

#pragma unroll
  for (int mi = 0; mi < 2; ++mi) {
#pragma unroll
    for (int ni = 0; ni < 2; ++ni) {
      int col = tileN + wn + ni * 32 + l31;
      float bcol = bias[col];
#pragma unroll
      for (int r = 0; r < 16; ++r) {
        int row = tileM + wm + mi * 32 + 4 * half + (r & 3) + 8 * (r >> 2);
        float val = acc[mi][ni][r] + bcol;
        if (ADD_X) val += xadd[(size_t)row * N + col];
        C[(size_t)row * N + col] = val;
      }
    }
  }
}

// ---- GEMM2: 256x256 8-phase pipelined bf16 GEMM, v4 (race-free quadrant port) ----
// 16x16x32 MFMA, phase = one C-quadrant x full K=64 (16 MFMA = 8 indep chains
// x depth 2). 8 waves (2Mx4N), per-wave 128x64 out = acc[8][4] of f32x4.
// Quadrant order per K-tile: (0,0)(0,1)(1,1)(1,0). ALL FOUR B quadrant sets
// held in registers (bf=nh0, bg=nh1) -> NO LDS re-reads; each buffer's LDS
// reads complete in 3 phases, leaving a 5-phase dead window for staging.
//
// v3's bug (fixed here): stage halves are ABSOLUTE row ranges (h=0: rows
// 0-127), read halves are PER-WAVE windows (wcol+nh*32) — different
// partitions, so interleaved per-half staging clobbered rows other waves
// still needed. v4 stages whole operands strictly inside dead windows:
//   reads:  P1 A(b0,mh0)+B(b0,nh0)[12]  P2 B(b0,nh1)[4]  P3 A(b0,mh1)[8]
//           P5 A(b1,mh0)+B(b1,nh0)[12]  P6 B(b1,nh1)[4]  P7 A(b1,mh1)[8]
//   stages: P1 B(b1)<-t+1 [Bs1 last read prev P6]
//           P4 A(b0)<-t+2 [As0 last read P3]   P5 B(b0)<-t+2 [Bs0 last read P2]
//           P8 A(b1)<-t+3 [As1 last read P7]
//   gates:  P4 vmcnt(4) completes buf1=t+1 (prev-P8 A + P1 B; slack 3-4 ph)
//           P8 vmcnt(4) completes buf0=t+2 (P4 A + P5 B; slack 3-4 ph)
// Loads never drain to 0 mid-loop; last iter: P4 vmcnt(0) drains.
#define BAR_FENCE() do { asm volatile("" ::: "memory"); \
  __builtin_amdgcn_s_barrier(); asm volatile("" ::: "memory"); } while (0)

template <bool ADD_X, int LDA, int LDB, int NOUT, int KTOT>
__global__ __launch_bounds__(512, 2) void gemm256_bt(
    const unsigned short* __restrict__ Amat,
    const unsigned short* __restrict__ Bmat,
    const float* __restrict__ bias,
    const float* __restrict__ xadd,
    float* __restrict__ C) {
  constexpr int NK  = KTOT / 64;          // 40 K-tiles
  constexpr int NI  = NK / 2;             // 20 iterations (2 tiles each)
  constexpr int NTN = NOUT / 256;         // 8 tile-cols
  constexpr int NWG = (NTOK / 256) * NTN; // 512 workgroups
  constexpr int PERX = NWG / 8;           // 64 per XCD

  __shared__ unsigned short As[2][256 * 64];  // 64 KiB
  __shared__ unsigned short Bs[2][256 * 64];  // 64 KiB

  const int tid  = threadIdx.x;
  const int lane = tid & 63;
  const int l15  = lane & 15;
  const int g4   = lane >> 4;           // 16x16x32 k-group (0..3)
  const int wave = tid >> 6;
  const int wrow = (wave >> 2) * 128;   // 2 wave-rows
  const int wcol = (wave & 3) * 64;     // 4 wave-cols

  // XCD-aware swizzle (512 % 8 == 0 -> bijective).
  const int bid   = blockIdx.x;
  const int wgid  = (bid & 7) * PERX + (bid >> 3);
  const int tileM = (wgid / NTN) * 256;
  const int tileN = (wgid % NTN) * 256;

  // Per-thread staging source (global-side XOR pre-swizzle; row&7 invariant
  // under +64/+128 row offsets, so one base pointer serves all half-tiles).
  const int row_lo = tid >> 3;                              // 0..63
  const int scol   = (((tid & 7) ^ (row_lo & 7)) << 3);
  const unsigned short* pA = Amat + (size_t)(tileM + row_lo) * LDA + scol;
  const unsigned short* pB = Bmat + (size_t)(tileN + row_lo) * LDB + scol;

#define GSTAGE_A(b, h, kt) do { \
  _Pragma("unroll") for (int j = 0; j < 2; ++j) { \
    const unsigned short* _s = pA + (size_t)((h) * 128 + j * 64) * LDA + (kt) * 64; \
    __builtin_amdgcn_global_load_lds((const __attribute__((address_space(1))) void*)_s, \
        (__attribute__((address_space(3))) void*)(&As[(b)][(h) * 8192 + (j * 512 + tid) * 8]), \
        16, 0, 0); \
  } \
} while (0)

#define GSTAGE_B(b, h, kt) do { \
  _Pragma("unroll") for (int j = 0; j < 2; ++j) { \
    const unsigned short* _s = pB + (size_t)((h) * 128 + j * 64) * LDB + (kt) * 64; \
    __builtin_amdgcn_global_load_lds((const __attribute__((address_space(1))) void*)_s, \
        (__attribute__((address_space(3))) void*)(&Bs[(b)][(h) * 8192 + (j * 512 + tid) * 8]), \
        16, 0, 0); \
  } \
} while (0)

  f32x4  acc[8][4] = {};   // 128 regs (AGPR side of unified file)
  bf16x8 af[4][2];         // A quadrant-half: 4 m-tiles x 2 ksteps (32 VGPR)
  bf16x8 bf[2][2];         // B nh=0 quadrant set (16 VGPR)
  bf16x8 bg[2][2];         // B nh=1 quadrant set (16 VGPR)

  // 16x16x32 fragment: lane holds row (l&15), k = (l>>4)*8.. within kstep*32.
  // LDS chunk c of row r holds global chunk c^(r&7) -> read chunk q^(r&7).
#define GREAD_A(b, mh) do { \
  _Pragma("unroll") for (int mt = 0; mt < 4; ++mt) { \
    const int _r = wrow + (mh) * 64 + mt * 16 + l15; \
    _Pragma("unroll") for (int ks = 0; ks < 2; ++ks) \
      af[mt][ks] = *(const bf16x8*)(&As[(b)][_r * 64 + (((ks * 4 + g4) ^ (_r & 7)) << 3)]); \
  } \
} while (0)

#define GREAD_B(b, nh, dst) do { \
  _Pragma("unroll") for (int nt = 0; nt < 2; ++nt) { \
    const int _r = wcol + (nh) * 32 + nt * 16 + l15; \
    _Pragma("unroll") for (int ks = 0; ks < 2; ++ks) \
      dst[nt][ks] = *(const bf16x8*)(&Bs[(b)][_r * 64 + (((ks * 4 + g4) ^ (_r & 7)) << 3)]); \
  } \
} while (0)

// 16 MFMA: 8 independent (mt,nt) chains x depth 2 (ks)
#define GMFMA_Q(mh, nh, breg) do { \
  _Pragma("unroll") for (int ks = 0; ks < 2; ++ks) \
    _Pragma("unroll") for (int mt = 0; mt < 4; ++mt) \
      _Pragma("unroll") for (int nt = 0; nt < 2; ++nt) \
        acc[(mh) * 4 + mt][(nh) * 2 + nt] = __builtin_amdgcn_mfma_f32_16x16x32_bf16( \
            af[mt][ks], breg[nt][ks], acc[(mh) * 4 + mt][(nh) * 2 + nt], 0, 0, 0); \
} while (0)

#define GTAIL(mh, nh, breg) do { \
  BAR_FENCE(); \
  asm volatile("s_waitcnt lgkmcnt(0)" ::: "memory"); \
  __builtin_amdgcn_sched_barrier(0); \
  __builtin_amdgcn_s_setprio(1); \
  GMFMA_Q(mh, nh, breg); \
  __builtin_amdgcn_s_setprio(0); \
  BAR_FENCE(); \
} while (0)

  // Prologue: buf0 <- tile0 (8 loads, oldest), buf1 <- A of tile1 (4 loads).
  // vmcnt(4): buf0 resident; buf1's A stays in flight (B(b1) staged at P1).
  GSTAGE_A(0, 0, 0); GSTAGE_A(0, 1, 0);
  GSTAGE_B(0, 0, 0); GSTAGE_B(0, 1, 0);
  GSTAGE_A(1, 0, 1); GSTAGE_A(1, 1, 1);
  asm volatile("s_waitcnt vmcnt(4)" ::: "memory");
  BAR_FENCE();

#define GITER(i2, FULL) do { \
  /* P1: quad(0,0) buf0; stage B(b1)<-tile i2+1 */ \
  GREAD_A(0, 0); GREAD_B(0, 0, bf); \
  GSTAGE_B(1, 0, (i2) + 1); GSTAGE_B(1, 1, (i2) + 1); \
  asm volatile("s_waitcnt lgkmcnt(8)" ::: "memory"); \
  GTAIL(0, 0, bf); \
  /* P2: quad(0,1) buf0 */ \
  GREAD_B(0, 1, bg); \
  GTAIL(0, 1, bg); \
  /* P3: quad(1,1) buf0 */ \
  GREAD_A(0, 1); \
  GTAIL(1, 1, bg); \
  /* P4: quad(1,0) buf0; stage A(b0)<-i2+2; gate buf1 = tile i2+1 */ \
  if (FULL) { GSTAGE_A(0, 0, (i2) + 2); GSTAGE_A(0, 1, (i2) + 2); \
              asm volatile("s_waitcnt vmcnt(4)" ::: "memory"); } \
  else      { asm volatile("s_waitcnt vmcnt(0)" ::: "memory"); } \
  GTAIL(1, 0, bf); \
  /* P5: quad(0,0) buf1; stage B(b0)<-i2+2 */ \
  GREAD_A(1, 0); GREAD_B(1, 0, bf); \
  if (FULL) { GSTAGE_B(0, 0, (i2) + 2); GSTAGE_B(0, 1, (i2) + 2); } \
  asm volatile("s_waitcnt lgkmcnt(8)" ::: "memory"); \
  GTAIL(0, 0, bf); \
  /* P6: quad(0,1) buf1 */ \
  GREAD_B(1, 1, bg); \
  GTAIL(0, 1, bg); \
  /* P7: quad(1,1) buf1 */ \
  GREAD_A(1, 1); \
  GTAIL(1, 1, bg); \
  /* P8: quad(1,0) buf1; stage A(b1)<-i2+3; gate buf0 = tile i2+2 */ \
  if (FULL) { GSTAGE_A(1, 0, (i2) + 3); GSTAGE_A(1, 1, (i2) + 3); \
              asm volatile("s_waitcnt vmcnt(4)" ::: "memory"); } \
  GTAIL(1, 0, bf); \
} while (0)

#pragma unroll 1
  for (int i = 0; i < NI - 1; ++i) GITER(2 * i, 1);
  GITER(2 * (NI - 1), 0);   // last iteration: P1's B(b1) stage only; P4 drains

#undef GITER
#undef GTAIL
#undef GMFMA_Q
#undef GREAD_B
#undef GREAD_A
#undef GSTAGE_B
#undef GSTAGE_A

  // Epilogue: 16x16 C/D layout col=lane&15, row=(lane>>4)*4+reg (m89/m91).
#pragma unroll
  for (int mt = 0; mt < 8; ++mt) {
#pragma unroll
    for (int nt = 0; nt < 4; ++nt) {
      const int col = tileN + wcol + nt * 16 + l15;
      const float bc = bias[col];
#pragma unroll
      for (int r = 0; r < 4; ++r) {
        const int row = tileM + wrow + mt * 16 + g4 * 4 + r;
        float val = acc[mt][nt][r] + bc;
        if (ADD_X) val += xadd[(size_t)row * NOUT + col];
        C[(size_t)row * NOUT + col] = val;
      }
    }
  }
}

extern "C" void kernel_launch(void* const* d_in, const int* in_sizes, int n_in,
                              void* d_out, int out_size, void* d_ws, size_t ws_size,
                              hipStream_t stream) {
  const float* x   = (const float*)d_in[0];
  const float* mem = (const float*)d_in[1];
  const float* Wv  = (const float*)d_in[2];
  const float* bv  = (const float*)d_in[3];
  const float* Wg  = (const float*)d_in[4];
  const float* bg  = (const float*)d_in[5];
  const float* td  = (const float*)d_in[6];
  const float* tf  = (const float*)d_in[7];
  float* out = (float*)d_out;  // [NTOK, D] output, then [B*M] next_memory

  // Workspace layout
  char* ws = (char*)d_ws;
  unsigned short* comb = (unsigned short*)ws;                              // [NTOK, KCOMB] bf16
  float* v = (float*)(ws + (size_t)NTOK * KCOMB * 2);                      // [NTOK, M] fp32
  unsigned short* WvB = (unsigned short*)((char*)v + (size_t)NTOK * M_DIM * 4);   // [M, D] bf16
  unsigned short* WgB = (unsigned short*)((char*)WvB + (size_t)M_DIM * D_DIM * 2); // [D, KCOMB] bf16
  float* P = (float*)WvB;  // aliases WvB (dead after GEMM1); P is 512 KB

  // 1. fused casts
  cast_all_kernel<<<XBLK + WVBLK + WGBLK, 256, 0, stream>>>(x, Wv, Wg, comb, WvB, WgB);

  // 2. v = x_bf16 . Wv^T + bv   (A = combined[:, :D] via lda=KCOMB)
  gemm_bt<false, 0><<<(NTOK / BM) * (M_DIM / BN), 256, 0, stream>>>(
      comb, KCOMB, WvB, D_DIM, bv, nullptr, v, M_DIM, D_DIM);

  // 3. parallel scan: chunk partials, then prefix-fold + replay
  recur_partial<<<B_DIM * NCHUNK, M_DIM, 0, stream>>>(v, td, P);
  recur_apply<<<B_DIM * NCHUNK, M_DIM, 0, stream>>>(
      v, mem, td, tf, P, comb, out + (size_t)NTOK * D_DIM);

  // 4. out = x + combined . Wg^T + bg   (256^2 8-phase kernel, v4 race-free)
  gemm256_bt<true, KCOMB, KCOMB, D_DIM, KCOMB>
      <<<(NTOK / 256) * (D_DIM / 256), 512, 0, stream>>>(comb, WgB, bg, x, out);
}

// Round 6
// 478.790 us; speedup vs baseline: 1.1095x; 1.0613x over previous
//
#include <hip/hip_runtime.h>
#include <hip/hip_bf16.h>
#include <cstdint>
#include <cstddef>

// Problem dims (fixed by reference)
#define B_DIM 4
#define T_DIM 4096
#define D_DIM 2048
#define M_DIM 512
#define NTOK  (B_DIM * T_DIM)     // 16384 rows
#define KCOMB (D_DIM + M_DIM)     // 2560
#define NCHUNK 64                 // chunks per chain for the parallel scan
#define CLEN   64                 // T / NCHUNK

typedef __attribute__((ext_vector_type(8)))  __bf16 bf16x8;  // MFMA A/B frag (4 VGPRs)
typedef __attribute__((ext_vector_type(16))) float  f32x16;  // 32x32 MFMA C/D frag
typedef __attribute__((ext_vector_type(4)))  float  f32x4;   // 16x16 MFMA C/D frag

__device__ __forceinline__ unsigned short f2bf(float f) {
  union { float f; unsigned u; } v; v.f = f;
  unsigned r = v.u + 0x7fffu + ((v.u >> 16) & 1u);  // RNE
  return (unsigned short)(r >> 16);
}

__device__ __forceinline__ float bf2f(unsigned short u) {
  union { unsigned u; float f; } v; v.u = ((unsigned)u) << 16;
  return v.f;
}

__device__ __forceinline__ float sigmoidf(float x) { return 1.0f / (1.0f + expf(-x)); }

// ---- fused casts: x -> comb[:, :D] (stride KCOMB), Wv -> WvB, Wg -> WgB ----
#define XBLK  ((NTOK * D_DIM / 4) / 256)            // 32768
#define WVBLK ((M_DIM * D_DIM / 4) / 256)           // 1024
#define WGBLK ((D_DIM * KCOMB / 4) / 256)           // 5120
__global__ void cast_all_kernel(const float* __restrict__ x, const float* __restrict__ Wv,
                                const float* __restrict__ Wg,
                                unsigned short* __restrict__ comb,
                                unsigned short* __restrict__ WvB,
                                unsigned short* __restrict__ WgB) {
  int bid = blockIdx.x;
  const float* src; unsigned short* dst; size_t soff, doff;
  if (bid < XBLK) {
    int idx = bid * 256 + threadIdx.x;
    int n = idx >> 9;                               // D/4 = 512 quads per row
    int c = (idx & 511) << 2;
    src = x;   soff = (size_t)n * D_DIM + c;
    dst = comb; doff = (size_t)n * KCOMB + c;
  } else if (bid < XBLK + WVBLK) {
    int idx = (bid - XBLK) * 256 + threadIdx.x;
    src = Wv;  soff = (size_t)idx * 4;
    dst = WvB; doff = (size_t)idx * 4;
  } else {
    int idx = (bid - XBLK - WVBLK) * 256 + threadIdx.x;
    src = Wg;  soff = (size_t)idx * 4;
    dst = WgB; doff = (size_t)idx * 4;
  }
  float4 v = *(const float4*)(src + soff);
  ushort4 o;
  o.x = f2bf(v.x); o.y = f2bf(v.y); o.z = f2bf(v.z); o.w = f2bf(v.w);
  *(ushort4*)(dst + doff) = o;
}

// ---- scan phase 1: per-chunk affine partial  P[b][c][m] = sum_i decay^{CLEN-1-i} v[...] ----
__global__ __launch_bounds__(M_DIM) void recur_partial(
    const float* __restrict__ v, const float* __restrict__ td, float* __restrict__ P) {
  int m = threadIdx.x;
  int b = blockIdx.x >> 6;
  int c = blockIdx.x & (NCHUNK - 1);
  float decay = sigmoidf(td[m]) * 0.9f + 0.1f;
  const float* vp = v + ((size_t)(b * T_DIM + c * CLEN)) * M_DIM + m;
  float p = 0.0f;
  for (int t0 = 0; t0 < CLEN; t0 += 8) {
    float vt[8];
#pragma unroll
    for (int u = 0; u < 8; ++u) vt[u] = vp[(size_t)(t0 + u) * M_DIM];
#pragma unroll
    for (int u = 0; u < 8; ++u) p = p * decay + vt[u];
  }
  P[(size_t)blockIdx.x * M_DIM + m] = p;
}

// ---- scan phases 2+3: fold prefix partials -> chunk start state, then replay chunk ----
__global__ __launch_bounds__(M_DIM) void recur_apply(
    const float* __restrict__ v, const float* __restrict__ mem0,
    const float* __restrict__ td, const float* __restrict__ tf,
    const float* __restrict__ P,
    unsigned short* __restrict__ comb, float* __restrict__ nmem) {
  int m = threadIdx.x;
  int b = blockIdx.x >> 6;
  int c = blockIdx.x & (NCHUNK - 1);
  float decay = sigmoidf(td[m]) * 0.9f + 0.1f;
  float first = sigmoidf(tf[m]);
  float dL = decay;  // decay^64 via 6 squarings
  dL = dL * dL; dL = dL * dL; dL = dL * dL; dL = dL * dL; dL = dL * dL; dL = dL * dL;

  float s = mem0[b * M_DIM + m];
  const float* Pp = P + (size_t)(b * NCHUNK) * M_DIM + m;
  for (int ci = 0; ci < c; ++ci)
    s = s * dL + Pp[(size_t)ci * M_DIM];

  const float* vp = v + ((size_t)(b * T_DIM + c * CLEN)) * M_DIM + m;
  unsigned short* wp = comb + ((size_t)(b * T_DIM + c * CLEN)) * KCOMB + D_DIM + m;
  for (int t0 = 0; t0 < CLEN; t0 += 8) {
    float vt[8];
#pragma unroll
    for (int u = 0; u < 8; ++u) vt[u] = vp[(size_t)(t0 + u) * M_DIM];
#pragma unroll
    for (int u = 0; u < 8; ++u) {
      wp[(size_t)(t0 + u) * KCOMB] = f2bf(vt[u] + s * first);
      s = s * decay + vt[u];
    }
  }
  if (c == NCHUNK - 1) nmem[b * M_DIM + m] = s;
}

// ---- GEMM1: bf16 GEMM, C[row,col] = sum_k A[row,k]*B[col,k] (+bias[col]) ----
// 128x128 tile, BK=64, 32x32x16 MFMA, 2-phase loop. Kept for the NTOK x 512
// shape (256^2 tiling would give only 128 workgroups = half-idle GPU).
#define BM 128
#define BN 128
#define BK 64

template <bool ADD_X, int MODE>
__global__ __launch_bounds__(256) void gemm_bt(
    const unsigned short* __restrict__ A, int lda,
    const unsigned short* __restrict__ B, int ldb,
    const float* __restrict__ bias, const float* __restrict__ xadd,
    float* __restrict__ C, int N, int K) {
  const int tid = threadIdx.x;
  const int lane = tid & 63;
  const int wave = tid >> 6;
  const int wm = (wave >> 1) * 64;   // wave row offset in tile
  const int wn = (wave & 1) * 64;    // wave col offset in tile
  const int l31 = lane & 31;
  const int half = lane >> 5;

  int tileM, tileN;
  {
    int idx = blockIdx.x;
    int xcd = idx & 7, local = idx >> 3;
    if (MODE == 1) {
      tileN = (xcd * 2 + (local & 1)) * BN;
      tileM = (local >> 1) * BM;
    } else {                    // GEMM1: 128x4 tiles
      tileM = (xcd * 16 + (local >> 2)) * BM;
      tileN = (local & 3) * BN;
    }
  }

  __shared__ unsigned short As[BM * BK];  // 16 KiB
  __shared__ unsigned short Bs[BN * BK];  // 16 KiB

  f32x16 acc[2][2] = {};

  for (int k0 = 0; k0 < K; k0 += BK) {
#pragma unroll
    for (int j = 0; j < 4; ++j) {
      int c = j * 256 + tid;
      int row = c >> 3;
      int kc = c & 7;
      int gkc = kc ^ (row & 7);
      const unsigned short* gA = A + (size_t)(tileM + row) * lda + k0 + gkc * 8;
      const unsigned short* gB = B + (size_t)(tileN + row) * ldb + k0 + gkc * 8;
      __builtin_amdgcn_global_load_lds((const __attribute__((address_space(1))) void*)gA,
                                       (__attribute__((address_space(3))) void*)(As + c * 8),
                                       16, 0, 0);
      __builtin_amdgcn_global_load_lds((const __attribute__((address_space(1))) void*)gB,
                                       (__attribute__((address_space(3))) void*)(Bs + c * 8),
                                       16, 0, 0);
    }
    __syncthreads();

#pragma unroll
    for (int s = 0; s < 4; ++s) {
      const int g = s * 2 + half;
      bf16x8 af[2], bfr[2];
#pragma unroll
      for (int i = 0; i < 2; ++i) {
        int ra = wm + i * 32 + l31;
        int rb = wn + i * 32 + l31;
        af[i]  = *(const bf16x8*)(As + ra * BK + ((g ^ (ra & 7)) * 8));
        bfr[i] = *(const bf16x8*)(Bs + rb * BK + ((g ^ (rb & 7)) * 8));
      }
#pragma unroll
      for (int mi = 0; mi < 2; ++mi)
#pragma unroll
        for (int ni = 0; ni < 2; ++ni)
          acc[mi][ni] = __builtin_amdgcn_mfma_f32_32x32x16_bf16(af[mi], bfr[ni], acc[mi][ni], 0, 0, 0);
    }
    __syncthreads();
  }

#pragma unroll
  for (int mi = 0; mi < 2; ++mi) {
#pragma unroll
    for (int ni = 0; ni < 2; ++ni) {
      int col = tileN + wn + ni * 32 + l31;
      float bcol = bias[col];
#pragma unroll
      for (int r = 0; r < 16; ++r) {
        int row = tileM + wm + mi * 32 + 4 * half + (r & 3) + 8 * (r >> 2);
        float val = acc[mi][ni][r] + bcol;
        if (ADD_X) val += xadd[(size_t)row * N + col];
        C[(size_t)row * N + col] = val;
      }
    }
  }
}

// ---- GEMM2: 256x256 8-phase pipelined bf16 GEMM, v5 ----
// v4 (race-free quadrant schedule, 0 bank conflicts) MINUS the blanket
// per-phase `s_waitcnt lgkmcnt(0)` + `sched_barrier(0)`. Rationale (r4
// post-mortem): the blanket wait forces every wave to drain ALL its phase
// reads before its FIRST MFMA, serializing the LDS pipe (~4.0k cyc/CU/iter)
// with the MFMA pipe (~4.1k cyc/SIMD/iter) -> 12.6k wall. The compiler's
// own fine-grained lgkmcnt(N) per ds_read->MFMA dep (m97 asm; rule #18 is
// for inline-asm reads only) lets each wave's MFMAs start as soon as their
// own operands land, overlapping the two pipes. Cross-wave safety is
// unchanged: every read is consumed by its own phase's MFMA (=> completed
// before that phase's end barrier), stages touch a region only >=1 barrier
// after its last read, vmcnt(4) gates at P4/P8 cover gload_lds->ds_read.
//
// Schedule (per iter i, tiles 2i in buf0 / 2i+1 in buf1):
//   reads:  P1 A(b0,mh0)+B(b0,nh0)[12]  P2 B(b0,nh1)[4]  P3 A(b0,mh1)[8]
//           P5 A(b1,mh0)+B(b1,nh0)[12]  P6 B(b1,nh1)[4]  P7 A(b1,mh1)[8]
//   stages: P1 B(b1)<-t+1   P4 A(b0)<-t+2   P5 B(b0)<-t+2   P8 A(b1)<-t+3
//   gates:  P4 vmcnt(4) completes buf1=t+1; P8 vmcnt(4) completes buf0=t+2
#define BAR_FENCE() do { asm volatile("" ::: "memory"); \
  __builtin_amdgcn_s_barrier(); asm volatile("" ::: "memory"); } while (0)

template <bool ADD_X, int LDA, int LDB, int NOUT, int KTOT>
__global__ __launch_bounds__(512, 2) void gemm256_bt(
    const unsigned short* __restrict__ Amat,
    const unsigned short* __restrict__ Bmat,
    const float* __restrict__ bias,
    const unsigned short* __restrict__ xadd,   // bf16, row stride LDA (comb)
    float* __restrict__ C) {
  constexpr int NK  = KTOT / 64;          // 40 K-tiles
  constexpr int NI  = NK / 2;             // 20 iterations (2 tiles each)
  constexpr int NTN = NOUT / 256;         // 8 tile-cols
  constexpr int NWG = (NTOK / 256) * NTN; // 512 workgroups
  constexpr int PERX = NWG / 8;           // 64 per XCD

  __shared__ unsigned short As[2][256 * 64];  // 64 KiB
  __shared__ unsigned short Bs[2][256 * 64];  // 64 KiB

  const int tid  = threadIdx.x;
  const int lane = tid & 63;
  const int l15  = lane & 15;
  const int g4   = lane >> 4;           // 16x16x32 k-group (0..3)
  const int wave = tid >> 6;
  const int wrow = (wave >> 2) * 128;   // 2 wave-rows
  const int wcol = (wave & 3) * 64;     // 4 wave-cols

  // XCD-aware swizzle (512 % 8 == 0 -> bijective).
  const int bid   = blockIdx.x;
  const int wgid  = (bid & 7) * PERX + (bid >> 3);
  const int tileM = (wgid / NTN) * 256;
  const int tileN = (wgid % NTN) * 256;

  // Per-thread staging source (global-side XOR pre-swizzle; row&7 invariant
  // under +64/+128 row offsets, so one base pointer serves all half-tiles).
  const int row_lo = tid >> 3;                              // 0..63
  const int scol   = (((tid & 7) ^ (row_lo & 7)) << 3);
  const unsigned short* pA = Amat + (size_t)(tileM + row_lo) * LDA + scol;
  const unsigned short* pB = Bmat + (size_t)(tileN + row_lo) * LDB + scol;

#define GSTAGE_A(b, h, kt) do { \
  _Pragma("unroll") for (int j = 0; j < 2; ++j) { \
    const unsigned short* _s = pA + (size_t)((h) * 128 + j * 64) * LDA + (kt) * 64; \
    __builtin_amdgcn_global_load_lds((const __attribute__((address_space(1))) void*)_s, \
        (__attribute__((address_space(3))) void*)(&As[(b)][(h) * 8192 + (j * 512 + tid) * 8]), \
        16, 0, 0); \
  } \
} while (0)

#define GSTAGE_B(b, h, kt) do { \
  _Pragma("unroll") for (int j = 0; j < 2; ++j) { \
    const unsigned short* _s = pB + (size_t)((h) * 128 + j * 64) * LDB + (kt) * 64; \
    __builtin_amdgcn_global_load_lds((const __attribute__((address_space(1))) void*)_s, \
        (__attribute__((address_space(3))) void*)(&Bs[(b)][(h) * 8192 + (j * 512 + tid) * 8]), \
        16, 0, 0); \
  } \
} while (0)

  f32x4  acc[8][4] = {};   // 128 regs (AGPR side of unified file)
  bf16x8 af[4][2];         // A quadrant-half: 4 m-tiles x 2 ksteps (32 VGPR)
  bf16x8 bf[2][2];         // B nh=0 quadrant set (16 VGPR)
  bf16x8 bg[2][2];         // B nh=1 quadrant set (16 VGPR)

  // 16x16x32 fragment: lane holds row (l&15), k = (l>>4)*8.. within kstep*32.
  // LDS chunk c of row r holds global chunk c^(r&7) -> read chunk q^(r&7).
#define GREAD_A(b, mh) do { \
  _Pragma("unroll") for (int mt = 0; mt < 4; ++mt) { \
    const int _r = wrow + (mh) * 64 + mt * 16 + l15; \
    _Pragma("unroll") for (int ks = 0; ks < 2; ++ks) \
      af[mt][ks] = *(const bf16x8*)(&As[(b)][_r * 64 + (((ks * 4 + g4) ^ (_r & 7)) << 3)]); \
  } \
} while (0)

#define GREAD_B(b, nh, dst) do { \
  _Pragma("unroll") for (int nt = 0; nt < 2; ++nt) { \
    const int _r = wcol + (nh) * 32 + nt * 16 + l15; \
    _Pragma("unroll") for (int ks = 0; ks < 2; ++ks) \
      dst[nt][ks] = *(const bf16x8*)(&Bs[(b)][_r * 64 + (((ks * 4 + g4) ^ (_r & 7)) << 3)]); \
  } \
} while (0)

// 16 MFMA: 8 independent (mt,nt) chains x depth 2 (ks)
#define GMFMA_Q(mh, nh, breg) do { \
  _Pragma("unroll") for (int ks = 0; ks < 2; ++ks) \
    _Pragma("unroll") for (int mt = 0; mt < 4; ++mt) \
      _Pragma("unroll") for (int nt = 0; nt < 2; ++nt) \
        acc[(mh) * 4 + mt][(nh) * 2 + nt] = __builtin_amdgcn_mfma_f32_16x16x32_bf16( \
            af[mt][ks], breg[nt][ks], acc[(mh) * 4 + mt][(nh) * 2 + nt], 0, 0, 0); \
} while (0)

// v5: no blanket lgkmcnt/sched_barrier — compiler emits per-dep lgkmcnt(N)
// so each wave's MFMAs interleave with its remaining LDS reads.
#define GTAIL(mh, nh, breg) do { \
  BAR_FENCE(); \
  __builtin_amdgcn_s_setprio(1); \
  GMFMA_Q(mh, nh, breg); \
  __builtin_amdgcn_s_setprio(0); \
  BAR_FENCE(); \
} while (0)

  // Prologue: buf0 <- tile0 (8 loads, oldest), buf1 <- A of tile1 (4 loads).
  // vmcnt(4): buf0 resident; buf1's A stays in flight (B(b1) staged at P1).
  GSTAGE_A(0, 0, 0); GSTAGE_A(0, 1, 0);
  GSTAGE_B(0, 0, 0); GSTAGE_B(0, 1, 0);
  GSTAGE_A(1, 0, 1); GSTAGE_A(1, 1, 1);
  asm volatile("s_waitcnt vmcnt(4)" ::: "memory");
  BAR_FENCE();

#define GITER(i2, FULL) do { \
  /* P1: quad(0,0) buf0; stage B(b1)<-tile i2+1 */ \
  GREAD_A(0, 0); GREAD_B(0, 0, bf); \
  GSTAGE_B(1, 0, (i2) + 1); GSTAGE_B(1, 1, (i2) + 1); \
  GTAIL(0, 0, bf); \
  /* P2: quad(0,1) buf0 */ \
  GREAD_B(0, 1, bg); \
  GTAIL(0, 1, bg); \
  /* P3: quad(1,1) buf0 */ \
  GREAD_A(0, 1); \
  GTAIL(1, 1, bg); \
  /* P4: quad(1,0) buf0; stage A(b0)<-i2+2; gate buf1 = tile i2+1 */ \
  if (FULL) { GSTAGE_A(0, 0, (i2) + 2); GSTAGE_A(0, 1, (i2) + 2); \
              asm volatile("s_waitcnt vmcnt(4)" ::: "memory"); } \
  else      { asm volatile("s_waitcnt vmcnt(0)" ::: "memory"); } \
  GTAIL(1, 0, bf); \
  /* P5: quad(0,0) buf1; stage B(b0)<-i2+2 */ \
  GREAD_A(1, 0); GREAD_B(1, 0, bf); \
  if (FULL) { GSTAGE_B(0, 0, (i2) + 2); GSTAGE_B(0, 1, (i2) + 2); } \
  GTAIL(0, 0, bf); \
  /* P6: quad(0,1) buf1 */ \
  GREAD_B(1, 1, bg); \
  GTAIL(0, 1, bg); \
  /* P7: quad(1,1) buf1 */ \
  GREAD_A(1, 1); \
  GTAIL(1, 1, bg); \
  /* P8: quad(1,0) buf1; stage A(b1)<-i2+3; gate buf0 = tile i2+2 */ \
  if (FULL) { GSTAGE_A(1, 0, (i2) + 3); GSTAGE_A(1, 1, (i2) + 3); \
              asm volatile("s_waitcnt vmcnt(4)" ::: "memory"); } \
  GTAIL(1, 0, bf); \
} while (0)

#pragma unroll 1
  for (int i = 0; i < NI - 1; ++i) GITER(2 * i, 1);
  GITER(2 * (NI - 1), 0);   // last iteration: P1's B(b1) stage only; P4 drains

#undef GITER
#undef GTAIL
#undef GMFMA_Q
#undef GREAD_B
#undef GREAD_A
#undef GSTAGE_B
#undef GSTAGE_A

  // Epilogue: 16x16 C/D layout col=lane&15, row=(lane>>4)*4+reg (m89/m91).
  // x-add reads bf16 x from comb (col < D region) — saves the fp32 x re-read.
#pragma unroll
  for (int mt = 0; mt < 8; ++mt) {
#pragma unroll
    for (int nt = 0; nt < 4; ++nt) {
      const int col = tileN + wcol + nt * 16 + l15;
      const float bc = bias[col];
#pragma unroll
      for (int r = 0; r < 4; ++r) {
        const int row = tileM + wrow + mt * 16 + g4 * 4 + r;
        float val = acc[mt][nt][r] + bc;
        if (ADD_X) val += bf2f(xadd[(size_t)row * LDA + col]);
        C[(size_t)row * NOUT + col] = val;
      }
    }
  }
}

extern "C" void kernel_launch(void* const* d_in, const int* in_sizes, int n_in,
                              void* d_out, int out_size, void* d_ws, size_t ws_size,
                              hipStream_t stream) {
  const float* x   = (const float*)d_in[0];
  const float* mem = (const float*)d_in[1];
  const float* Wv  = (const float*)d_in[2];
  const float* bv  = (const float*)d_in[3];
  const float* Wg  = (const float*)d_in[4];
  const float* bg  = (const float*)d_in[5];
  const float* td  = (const float*)d_in[6];
  const float* tf  = (const float*)d_in[7];
  float* out = (float*)d_out;  // [NTOK, D] output, then [B*M] next_memory

  // Workspace layout
  char* ws = (char*)d_ws;
  unsigned short* comb = (unsigned short*)ws;                              // [NTOK, KCOMB] bf16
  float* v = (float*)(ws + (size_t)NTOK * KCOMB * 2);                      // [NTOK, M] fp32
  unsigned short* WvB = (unsigned short*)((char*)v + (size_t)NTOK * M_DIM * 4);   // [M, D] bf16
  unsigned short* WgB = (unsigned short*)((char*)WvB + (size_t)M_DIM * D_DIM * 2); // [D, KCOMB] bf16
  float* P = (float*)WvB;  // aliases WvB (dead after GEMM1); P is 512 KB

  // 1. fused casts
  cast_all_kernel<<<XBLK + WVBLK + WGBLK, 256, 0, stream>>>(x, Wv, Wg, comb, WvB, WgB);

  // 2. v = x_bf16 . Wv^T + bv   (A = combined[:, :D] via lda=KCOMB)
  gemm_bt<false, 0><<<(NTOK / BM) * (M_DIM / BN), 256, 0, stream>>>(
      comb, KCOMB, WvB, D_DIM, bv, nullptr, v, M_DIM, D_DIM);

  // 3. parallel scan: chunk partials, then prefix-fold + replay
  recur_partial<<<B_DIM * NCHUNK, M_DIM, 0, stream>>>(v, td, P);
  recur_apply<<<B_DIM * NCHUNK, M_DIM, 0, stream>>>(
      v, mem, td, tf, P, comb, out + (size_t)NTOK * D_DIM);

  // 4. out = x + combined . Wg^T + bg   (256^2 8-phase kernel, v5)
  gemm256_bt<true, KCOMB, KCOMB, D_DIM, KCOMB>
      <<<(NTOK / 256) * (D_DIM / 256), 512, 0, stream>>>(comb, WgB, bg, comb, out);
}

// Round 7
// 473.037 us; speedup vs baseline: 1.1230x; 1.0122x over previous
//
#include <hip/hip_runtime.h>
#include <hip/hip_bf16.h>
#include <cstdint>
#include <cstddef>

// Problem dims (fixed by reference)
#define B_DIM 4
#define T_DIM 4096
#define D_DIM 2048
#define M_DIM 512
#define NTOK  (B_DIM * T_DIM)     // 16384 rows
#define KCOMB (D_DIM + M_DIM)     // 2560
#define NCHUNK 64                 // chunks per chain for the parallel scan
#define CLEN   64                 // T / NCHUNK

typedef __attribute__((ext_vector_type(8)))  __bf16 bf16x8;  // MFMA A/B frag (4 VGPRs)
typedef __attribute__((ext_vector_type(16))) float  f32x16;  // 32x32 MFMA C/D frag
typedef __attribute__((ext_vector_type(4)))  float  f32x4;   // 16x16 MFMA C/D frag

__device__ __forceinline__ unsigned short f2bf(float f) {
  union { float f; unsigned u; } v; v.f = f;
  unsigned r = v.u + 0x7fffu + ((v.u >> 16) & 1u);  // RNE
  return (unsigned short)(r >> 16);
}

__device__ __forceinline__ float bf2f(unsigned short u) {
  union { unsigned u; float f; } v; v.u = ((unsigned)u) << 16;
  return v.f;
}

__device__ __forceinline__ float sigmoidf(float x) { return 1.0f / (1.0f + expf(-x)); }

// ---- fused casts: x -> comb[:, :D] (stride KCOMB), Wv -> WvB, Wg -> WgB ----
#define XBLK  ((NTOK * D_DIM / 4) / 256)            // 32768
#define WVBLK ((M_DIM * D_DIM / 4) / 256)           // 1024
#define WGBLK ((D_DIM * KCOMB / 4) / 256)           // 5120
__global__ void cast_all_kernel(const float* __restrict__ x, const float* __restrict__ Wv,
                                const float* __restrict__ Wg,
                                unsigned short* __restrict__ comb,
                                unsigned short* __restrict__ WvB,
                                unsigned short* __restrict__ WgB) {
  int bid = blockIdx.x;
  const float* src; unsigned short* dst; size_t soff, doff;
  if (bid < XBLK) {
    int idx = bid * 256 + threadIdx.x;
    int n = idx >> 9;                               // D/4 = 512 quads per row
    int c = (idx & 511) << 2;
    src = x;   soff = (size_t)n * D_DIM + c;
    dst = comb; doff = (size_t)n * KCOMB + c;
  } else if (bid < XBLK + WVBLK) {
    int idx = (bid - XBLK) * 256 + threadIdx.x;
    src = Wv;  soff = (size_t)idx * 4;
    dst = WvB; doff = (size_t)idx * 4;
  } else {
    int idx = (bid - XBLK - WVBLK) * 256 + threadIdx.x;
    src = Wg;  soff = (size_t)idx * 4;
    dst = WgB; doff = (size_t)idx * 4;
  }
  float4 v = *(const float4*)(src + soff);
  ushort4 o;
  o.x = f2bf(v.x); o.y = f2bf(v.y); o.z = f2bf(v.z); o.w = f2bf(v.w);
  *(ushort4*)(dst + doff) = o;
}

// ---- scan phase 1: per-chunk affine partial  P[b][c][m] = sum_i decay^{CLEN-1-i} v[...] ----
__global__ __launch_bounds__(M_DIM) void recur_partial(
    const float* __restrict__ v, const float* __restrict__ td, float* __restrict__ P) {
  int m = threadIdx.x;
  int b = blockIdx.x >> 6;
  int c = blockIdx.x & (NCHUNK - 1);
  float decay = sigmoidf(td[m]) * 0.9f + 0.1f;
  const float* vp = v + ((size_t)(b * T_DIM + c * CLEN)) * M_DIM + m;
  float p = 0.0f;
  for (int t0 = 0; t0 < CLEN; t0 += 8) {
    float vt[8];
#pragma unroll
    for (int u = 0; u < 8; ++u) vt[u] = vp[(size_t)(t0 + u) * M_DIM];
#pragma unroll
    for (int u = 0; u < 8; ++u) p = p * decay + vt[u];
  }
  P[(size_t)blockIdx.x * M_DIM + m] = p;
}

// ---- scan phases 2+3: fold prefix partials -> chunk start state, then replay chunk ----
__global__ __launch_bounds__(M_DIM) void recur_apply(
    const float* __restrict__ v, const float* __restrict__ mem0,
    const float* __restrict__ td, const float* __restrict__ tf,
    const float* __restrict__ P,
    unsigned short* __restrict__ comb, float* __restrict__ nmem) {
  int m = threadIdx.x;
  int b = blockIdx.x >> 6;
  int c = blockIdx.x & (NCHUNK - 1);
  float decay = sigmoidf(td[m]) * 0.9f + 0.1f;
  float first = sigmoidf(tf[m]);
  float dL = decay;  // decay^64 via 6 squarings
  dL = dL * dL; dL = dL * dL; dL = dL * dL; dL = dL * dL; dL = dL * dL; dL = dL * dL;

  float s = mem0[b * M_DIM + m];
  const float* Pp = P + (size_t)(b * NCHUNK) * M_DIM + m;
  for (int ci = 0; ci < c; ++ci)
    s = s * dL + Pp[(size_t)ci * M_DIM];

  const float* vp = v + ((size_t)(b * T_DIM + c * CLEN)) * M_DIM + m;
  unsigned short* wp = comb + ((size_t)(b * T_DIM + c * CLEN)) * KCOMB + D_DIM + m;
  for (int t0 = 0; t0 < CLEN; t0 += 8) {
    float vt[8];
#pragma unroll
    for (int u = 0; u < 8; ++u) vt[u] = vp[(size_t)(t0 + u) * M_DIM];
#pragma unroll
    for (int u = 0; u < 8; ++u) {
      wp[(size_t)(t0 + u) * KCOMB] = f2bf(vt[u] + s * first);
      s = s * decay + vt[u];
    }
  }
  if (c == NCHUNK - 1) nmem[b * M_DIM + m] = s;
}

// ---- GEMM1: bf16 GEMM, C[row,col] = sum_k A[row,k]*B[col,k] (+bias[col]) ----
// 128x128 tile, BK=64, 32x32x16 MFMA, 2-phase loop. Kept for the NTOK x 512
// shape (256^2 tiling would give only 128 workgroups = half-idle GPU).
#define BM 128
#define BN 128
#define BK 64

template <bool ADD_X, int MODE>
__global__ __launch_bounds__(256) void gemm_bt(
    const unsigned short* __restrict__ A, int lda,
    const unsigned short* __restrict__ B, int ldb,
    const float* __restrict__ bias, const float* __restrict__ xadd,
    float* __restrict__ C, int N, int K) {
  const int tid = threadIdx.x;
  const int lane = tid & 63;
  const int wave = tid >> 6;
  const int wm = (wave >> 1) * 64;   // wave row offset in tile
  const int wn = (wave & 1) * 64;    // wave col offset in tile
  const int l31 = lane & 31;
  const int half = lane >> 5;

  int tileM, tileN;
  {
    int idx = blockIdx.x;
    int xcd = idx & 7, local = idx >> 3;
    if (MODE == 1) {
      tileN = (xcd * 2 + (local & 1)) * BN;
      tileM = (local >> 1) * BM;
    } else {                    // GEMM1: 128x4 tiles
      tileM = (xcd * 16 + (local >> 2)) * BM;
      tileN = (local & 3) * BN;
    }
  }

  __shared__ unsigned short As[BM * BK];  // 16 KiB
  __shared__ unsigned short Bs[BN * BK];  // 16 KiB

  f32x16 acc[2][2] = {};

  for (int k0 = 0; k0 < K; k0 += BK) {
#pragma unroll
    for (int j = 0; j < 4; ++j) {
      int c = j * 256 + tid;
      int row = c >> 3;
      int kc = c & 7;
      int gkc = kc ^ (row & 7);
      const unsigned short* gA = A + (size_t)(tileM + row) * lda + k0 + gkc * 8;
      const unsigned short* gB = B + (size_t)(tileN + row) * ldb + k0 + gkc * 8;
      __builtin_amdgcn_global_load_lds((const __attribute__((address_space(1))) void*)gA,
                                       (__attribute__((address_space(3))) void*)(As + c * 8),
                                       16, 0, 0);
      __builtin_amdgcn_global_load_lds((const __attribute__((address_space(1))) void*)gB,
                                       (__attribute__((address_space(3))) void*)(Bs + c * 8),
                                       16, 0, 0);
    }
    __syncthreads();

#pragma unroll
    for (int s = 0; s < 4; ++s) {
      const int g = s * 2 + half;
      bf16x8 af[2], bfr[2];
#pragma unroll
      for (int i = 0; i < 2; ++i) {
        int ra = wm + i * 32 + l31;
        int rb = wn + i * 32 + l31;
        af[i]  = *(const bf16x8*)(As + ra * BK + ((g ^ (ra & 7)) * 8));
        bfr[i] = *(const bf16x8*)(Bs + rb * BK + ((g ^ (rb & 7)) * 8));
      }
#pragma unroll
      for (int mi = 0; mi < 2; ++mi)
#pragma unroll
        for (int ni = 0; ni < 2; ++ni)
          acc[mi][ni] = __builtin_amdgcn_mfma_f32_32x32x16_bf16(af[mi], bfr[ni], acc[mi][ni], 0, 0, 0);
    }
    __syncthreads();
  }

#pragma unroll
  for (int mi = 0; mi < 2; ++mi) {
#pragma unroll
    for (int ni = 0; ni < 2; ++ni) {
      int col = tileN + wn + ni * 32 + l31;
      float bcol = bias[col];
#pragma unroll
      for (int r = 0; r < 16; ++r) {
        int row = tileM + wm + mi * 32 + 4 * half + (r & 3) + 8 * (r >> 2);
        float val = acc[mi][ni][r] + bcol;
        if (ADD_X) val += xadd[(size_t)row * N + col];
        C[(size_t)row * N + col] = val;
      }
    }
  }
}

// ---- GEMM2: 256x256 pipelined bf16 GEMM, v6 (4 barriers/iter) ----
// r6 theory: 16 barriers/iter force phase-additivity — all 8 waves' ds_reads
// drain before any MFMA starts (fair LDS round-robin completes them together),
// so wall = sum(read_drain + MFMA) per phase. v6 keeps only the 4 barriers
// that are load-bearing:
//   BAR_A: after buf0's last LDS read (reads complete before their own MFMAs,
//          which precede the barrier) -> legal to restage buf0
//   BAR_B: after vmcnt(8) gate -> buf1 collectively ready (vmcnt is per-wave;
//          the barrier makes it collective)
//   BAR_C/BAR_D: same pair for buf1/buf0.
// Between barriers, a 3-quadrant window (24 reads + 48 MFMA per wave) flows
// freely: compiler's per-dep lgkmcnt lets early-serviced waves start MFMA
// while laggards' reads drain -> LDS and MFMA pipes overlap.
//
// Stage/queue schedule (per-wave vmem instruction counts, 4 per operand):
//   W0: stage B(b1)<-t+1 [outstanding 8]; reads+MFMA quads (0,0)(0,1)(1,1) buf0
//   BAR_A; stage A(b0),B(b0)<-t+2 [16]; quad(1,0) buf0 (reg-only);
//   vmcnt(8) [drains A(b1)+B(b1) = buf1]; BAR_B
//   W1: reads+MFMA quads (0,0)(0,1)(1,1) buf1
//   BAR_C; stage A(b1)<-t+3 [12]; quad(1,0) buf1; vmcnt(4) [drains buf0]; BAR_D
// Every staged region has >=1 barrier after its last consumed read; every
// buffer's fresh content is vmcnt+barrier gated before first read.
#define BAR_FENCE() do { asm volatile("" ::: "memory"); \
  __builtin_amdgcn_s_barrier(); asm volatile("" ::: "memory"); } while (0)

template <bool ADD_X, int LDA, int LDB, int NOUT, int KTOT>
__global__ __launch_bounds__(512, 2) void gemm256_bt(
    const unsigned short* __restrict__ Amat,
    const unsigned short* __restrict__ Bmat,
    const float* __restrict__ bias,
    const unsigned short* __restrict__ xadd,   // bf16, row stride LDA (comb)
    float* __restrict__ C) {
  constexpr int NK  = KTOT / 64;          // 40 K-tiles
  constexpr int NI  = NK / 2;             // 20 iterations (2 tiles each)
  constexpr int NTN = NOUT / 256;         // 8 tile-cols
  constexpr int NWG = (NTOK / 256) * NTN; // 512 workgroups
  constexpr int PERX = NWG / 8;           // 64 per XCD

  __shared__ unsigned short As[2][256 * 64];  // 64 KiB
  __shared__ unsigned short Bs[2][256 * 64];  // 64 KiB

  const int tid  = threadIdx.x;
  const int lane = tid & 63;
  const int l15  = lane & 15;
  const int g4   = lane >> 4;           // 16x16x32 k-group (0..3)
  const int wave = tid >> 6;
  const int wrow = (wave >> 2) * 128;   // 2 wave-rows
  const int wcol = (wave & 3) * 64;     // 4 wave-cols

  // XCD-aware swizzle (512 % 8 == 0 -> bijective).
  const int bid   = blockIdx.x;
  const int wgid  = (bid & 7) * PERX + (bid >> 3);
  const int tileM = (wgid / NTN) * 256;
  const int tileN = (wgid % NTN) * 256;

  // Per-thread staging source (global-side XOR pre-swizzle; row&7 invariant
  // under +64/+128 row offsets, so one base pointer serves all half-tiles).
  const int row_lo = tid >> 3;                              // 0..63
  const int scol   = (((tid & 7) ^ (row_lo & 7)) << 3);
  const unsigned short* pA = Amat + (size_t)(tileM + row_lo) * LDA + scol;
  const unsigned short* pB = Bmat + (size_t)(tileN + row_lo) * LDB + scol;

#define GSTAGE_A(b, h, kt) do { \
  _Pragma("unroll") for (int j = 0; j < 2; ++j) { \
    const unsigned short* _s = pA + (size_t)((h) * 128 + j * 64) * LDA + (kt) * 64; \
    __builtin_amdgcn_global_load_lds((const __attribute__((address_space(1))) void*)_s, \
        (__attribute__((address_space(3))) void*)(&As[(b)][(h) * 8192 + (j * 512 + tid) * 8]), \
        16, 0, 0); \
  } \
} while (0)

#define GSTAGE_B(b, h, kt) do { \
  _Pragma("unroll") for (int j = 0; j < 2; ++j) { \
    const unsigned short* _s = pB + (size_t)((h) * 128 + j * 64) * LDB + (kt) * 64; \
    __builtin_amdgcn_global_load_lds((const __attribute__((address_space(1))) void*)_s, \
        (__attribute__((address_space(3))) void*)(&Bs[(b)][(h) * 8192 + (j * 512 + tid) * 8]), \
        16, 0, 0); \
  } \
} while (0)

  f32x4  acc[8][4] = {};   // 128 regs (AGPR side of unified file)
  bf16x8 af[4][2];         // A quadrant-half: 4 m-tiles x 2 ksteps (32 VGPR)
  bf16x8 bf[2][2];         // B nh=0 quadrant set (16 VGPR)
  bf16x8 bg[2][2];         // B nh=1 quadrant set (16 VGPR)

  // 16x16x32 fragment: lane holds row (l&15), k = (l>>4)*8.. within kstep*32.
  // LDS chunk c of row r holds global chunk c^(r&7) -> read chunk q^(r&7).
#define GREAD_A(b, mh) do { \
  _Pragma("unroll") for (int mt = 0; mt < 4; ++mt) { \
    const int _r = wrow + (mh) * 64 + mt * 16 + l15; \
    _Pragma("unroll") for (int ks = 0; ks < 2; ++ks) \
      af[mt][ks] = *(const bf16x8*)(&As[(b)][_r * 64 + (((ks * 4 + g4) ^ (_r & 7)) << 3)]); \
  } \
} while (0)

#define GREAD_B(b, nh, dst) do { \
  _Pragma("unroll") for (int nt = 0; nt < 2; ++nt) { \
    const int _r = wcol + (nh) * 32 + nt * 16 + l15; \
    _Pragma("unroll") for (int ks = 0; ks < 2; ++ks) \
      dst[nt][ks] = *(const bf16x8*)(&Bs[(b)][_r * 64 + (((ks * 4 + g4) ^ (_r & 7)) << 3)]); \
  } \
} while (0)

// 16 MFMA: 8 independent (mt,nt) chains x depth 2 (ks)
#define GMFMA_Q(mh, nh, breg) do { \
  __builtin_amdgcn_s_setprio(1); \
  _Pragma("unroll") for (int ks = 0; ks < 2; ++ks) \
    _Pragma("unroll") for (int mt = 0; mt < 4; ++mt) \
      _Pragma("unroll") for (int nt = 0; nt < 2; ++nt) \
        acc[(mh) * 4 + mt][(nh) * 2 + nt] = __builtin_amdgcn_mfma_f32_16x16x32_bf16( \
            af[mt][ks], breg[nt][ks], acc[(mh) * 4 + mt][(nh) * 2 + nt], 0, 0, 0); \
  __builtin_amdgcn_s_setprio(0); \
} while (0)

  // Prologue: buf0 <- tile0 (8 loads, oldest), buf1 <- A of tile1 (4 loads).
  // vmcnt(4): buf0 resident; buf1's A stays in flight (B(b1) staged in W0).
  GSTAGE_A(0, 0, 0); GSTAGE_A(0, 1, 0);
  GSTAGE_B(0, 0, 0); GSTAGE_B(0, 1, 0);
  GSTAGE_A(1, 0, 1); GSTAGE_A(1, 1, 1);
  asm volatile("s_waitcnt vmcnt(4)" ::: "memory");
  BAR_FENCE();

#define GITER(i2, FULL) do { \
  /* ---- window W0: buf0 = tile i2; stage B(b1)<-i2+1 ---- */ \
  GSTAGE_B(1, 0, (i2) + 1); GSTAGE_B(1, 1, (i2) + 1); \
  GREAD_A(0, 0); GREAD_B(0, 0, bf); \
  GMFMA_Q(0, 0, bf); \
  GREAD_B(0, 1, bg); \
  GMFMA_Q(0, 1, bg); \
  GREAD_A(0, 1); \
  GMFMA_Q(1, 1, bg); \
  BAR_FENCE();  /* BAR_A: buf0 LDS reads all consumed */ \
  if (FULL) { GSTAGE_A(0, 0, (i2) + 2); GSTAGE_A(0, 1, (i2) + 2); \
              GSTAGE_B(0, 0, (i2) + 2); GSTAGE_B(0, 1, (i2) + 2); } \
  GMFMA_Q(1, 0, bf);  /* register-only, overlaps stage issue + vmcnt drain */ \
  if (FULL) asm volatile("s_waitcnt vmcnt(8)" ::: "memory"); \
  else      asm volatile("s_waitcnt vmcnt(0)" ::: "memory"); \
  BAR_FENCE();  /* BAR_B: buf1 = tile i2+1 ready */ \
  /* ---- window W1: buf1 = tile i2+1 ---- */ \
  GREAD_A(1, 0); GREAD_B(1, 0, bf); \
  GMFMA_Q(0, 0, bf); \
  GREAD_B(1, 1, bg); \
  GMFMA_Q(0, 1, bg); \
  GREAD_A(1, 1); \
  GMFMA_Q(1, 1, bg); \
  BAR_FENCE();  /* BAR_C: buf1 LDS reads all consumed */ \
  if (FULL) { GSTAGE_A(1, 0, (i2) + 3); GSTAGE_A(1, 1, (i2) + 3); } \
  GMFMA_Q(1, 0, bf); \
  if (FULL) { asm volatile("s_waitcnt vmcnt(4)" ::: "memory"); \
              BAR_FENCE(); }  /* BAR_D: buf0 = tile i2+2 ready */ \
} while (0)

#pragma unroll 1
  for (int i = 0; i < NI - 1; ++i) GITER(2 * i, 1);
  GITER(2 * (NI - 1), 0);   // last iter: vmcnt(0) at the W0 gate; no trailing gate

#undef GITER
#undef GMFMA_Q
#undef GREAD_B
#undef GREAD_A
#undef GSTAGE_B
#undef GSTAGE_A

  // Epilogue: 16x16 C/D layout col=lane&15, row=(lane>>4)*4+reg (m89/m91).
  // x-add reads bf16 x from comb (col < D region) — saves the fp32 x re-read.
#pragma unroll
  for (int mt = 0; mt < 8; ++mt) {
#pragma unroll
    for (int nt = 0; nt < 4; ++nt) {
      const int col = tileN + wcol + nt * 16 + l15;
      const float bc = bias[col];
#pragma unroll
      for (int r = 0; r < 4; ++r) {
        const int row = tileM + wrow + mt * 16 + g4 * 4 + r;
        float val = acc[mt][nt][r] + bc;
        if (ADD_X) val += bf2f(xadd[(size_t)row * LDA + col]);
        C[(size_t)row * NOUT + col] = val;
      }
    }
  }
}

extern "C" void kernel_launch(void* const* d_in, const int* in_sizes, int n_in,
                              void* d_out, int out_size, void* d_ws, size_t ws_size,
                              hipStream_t stream) {
  const float* x   = (const float*)d_in[0];
  const float* mem = (const float*)d_in[1];
  const float* Wv  = (const float*)d_in[2];
  const float* bv  = (const float*)d_in[3];
  const float* Wg  = (const float*)d_in[4];
  const float* bg  = (const float*)d_in[5];
  const float* td  = (const float*)d_in[6];
  const float* tf  = (const float*)d_in[7];
  float* out = (float*)d_out;  // [NTOK, D] output, then [B*M] next_memory

  // Workspace layout
  char* ws = (char*)d_ws;
  unsigned short* comb = (unsigned short*)ws;                              // [NTOK, KCOMB] bf16
  float* v = (float*)(ws + (size_t)NTOK * KCOMB * 2);                      // [NTOK, M] fp32
  unsigned short* WvB = (unsigned short*)((char*)v + (size_t)NTOK * M_DIM * 4);   // [M, D] bf16
  unsigned short* WgB = (unsigned short*)((char*)WvB + (size_t)M_DIM * D_DIM * 2); // [D, KCOMB] bf16
  float* P = (float*)WvB;  // aliases WvB (dead after GEMM1); P is 512 KB

  // 1. fused casts
  cast_all_kernel<<<XBLK + WVBLK + WGBLK, 256, 0, stream>>>(x, Wv, Wg, comb, WvB, WgB);

  // 2. v = x_bf16 . Wv^T + bv   (A = combined[:, :D] via lda=KCOMB)
  gemm_bt<false, 0><<<(NTOK / BM) * (M_DIM / BN), 256, 0, stream>>>(
      comb, KCOMB, WvB, D_DIM, bv, nullptr, v, M_DIM, D_DIM);

  // 3. parallel scan: chunk partials, then prefix-fold + replay
  recur_partial<<<B_DIM * NCHUNK, M_DIM, 0, stream>>>(v, td, P);
  recur_apply<<<B_DIM * NCHUNK, M_DIM, 0, stream>>>(
      v, mem, td, tf, P, comb, out + (size_t)NTOK * D_DIM);

  // 4. out = x + combined . Wg^T + bg   (256^2 4-barrier kernel, v6)
  gemm256_bt<true, KCOMB, KCOMB, D_DIM, KCOMB>
      <<<(NTOK / 256) * (D_DIM / 256), 512, 0, stream>>>(comb, WgB, bg, comb, out);
}